// Round 3
// baseline (918.650 us; speedup 1.0000x reference)
//
#include <hip/hip_runtime.h>
#include <hip/hip_bf16.h>

#define N_NODES 50000
#define E_EDGES 800000
#define G_GRAPHS 64

// ---------------- workspace layout (4-byte words) ----------------
constexpr size_t O_CNT  = 0;        // int[100000]   per-node in-degree (sc then fc)
constexpr size_t O_CUR  = 102400;   // int[100000]   scatter cursors
constexpr size_t O_POOL = 204800;   // float[16384]  [G][256] pooled (sc|fc)
constexpr size_t O_ROW  = 221184;   // int[100000]   CSR row starts (excl scan)
constexpr size_t O_BS   = 323584;   // int[512]      scan block sums
constexpr size_t O_ES   = 324608;   // int[1600000]  src ids sorted by dst
constexpr size_t O_WT   = 1924608;  // float[8*16384] transposed weights
constexpr size_t O_MEAN = 2055680;  // float[50000*128]
constexpr size_t O_H    = 8455680;  // float[50000*128]
constexpr size_t ZERO_BYTES = O_ROW * 4;   // cnt + cursor + pool zeroed

// ---------------- CSR build ----------------
__global__ void hist_kernel(const int* __restrict__ sc_dst, const int* __restrict__ fc_dst,
                            int* __restrict__ cnt) {
    int e = blockIdx.x * blockDim.x + threadIdx.x;
    if (e < E_EDGES) atomicAdd(&cnt[sc_dst[e]], 1);
    else if (e < 2 * E_EDGES) atomicAdd(&cnt[N_NODES + fc_dst[e - E_EDGES]], 1);
}

__global__ void scan_blocks(const int* __restrict__ cnt, int* __restrict__ exsc,
                            int* __restrict__ bsums, int n) {
    __shared__ int wsum[8];
    int i = blockIdx.x * 256 + threadIdx.x;
    int v = (i < n) ? cnt[i] : 0;
    int lane = threadIdx.x & 63;
    int incl = v;
    #pragma unroll
    for (int d = 1; d < 64; d <<= 1) {
        int t = __shfl_up(incl, d, 64);
        if (lane >= d) incl += t;
    }
    int wid = threadIdx.x >> 6;
    if (lane == 63) wsum[wid] = incl;
    __syncthreads();
    int pre = 0;
    for (int w = 0; w < wid; ++w) pre += wsum[w];
    incl += pre;
    if (i < n) exsc[i] = incl - v;
    if (threadIdx.x == 255) bsums[blockIdx.x] = incl;
}

__global__ void scan_sums(int* __restrict__ bsums, int nb) {
    __shared__ int wsum[8];
    int t = threadIdx.x;          // 512 threads
    int v = (t < nb) ? bsums[t] : 0;
    int lane = t & 63;
    int incl = v;
    #pragma unroll
    for (int d = 1; d < 64; d <<= 1) {
        int u = __shfl_up(incl, d, 64);
        if (lane >= d) incl += u;
    }
    int wid = t >> 6;
    if (lane == 63) wsum[wid] = incl;
    __syncthreads();
    int pre = 0;
    for (int w = 0; w < wid; ++w) pre += wsum[w];
    incl += pre;
    bsums[t] = incl - v;          // exclusive, in place (buffer is 512 ints)
}

__global__ void scan_add(int* __restrict__ exsc, const int* __restrict__ boffs, int n) {
    int i = blockIdx.x * 256 + threadIdx.x;
    if (i < n) exsc[i] += boffs[blockIdx.x];
}

__global__ void scatter_kernel(const int* __restrict__ sc_e, const int* __restrict__ fc_e,
                               const int* __restrict__ row, int* __restrict__ cur,
                               int* __restrict__ es) {
    int e = blockIdx.x * blockDim.x + threadIdx.x;
    if (e < E_EDGES) {
        int src = sc_e[e];
        int dst = sc_e[E_EDGES + e];
        int pos = atomicAdd(&cur[dst], 1);
        es[row[dst] + pos] = src;
    } else if (e < 2 * E_EDGES) {
        int ee = e - E_EDGES;
        int src = fc_e[ee];
        int dst = fc_e[E_EDGES + ee];
        int pos = atomicAdd(&cur[N_NODES + dst], 1);
        es[row[N_NODES + dst] + pos] = src;
    }
}

// ---------------- weight transpose: WT[k][o] = W[o][k] ----------------
__global__ void transpose_weights(const float* w0, const float* w1, const float* w2, const float* w3,
                                  const float* w4, const float* w5, const float* w6, const float* w7,
                                  float* __restrict__ wt) {
    const float* W;
    int m = blockIdx.y;
    switch (m) {
        case 0: W = w0; break; case 1: W = w1; break;
        case 2: W = w2; break; case 3: W = w3; break;
        case 4: W = w4; break; case 5: W = w5; break;
        case 6: W = w6; break; default: W = w7; break;
    }
    int i = blockIdx.x * 256 + threadIdx.x;   // grid.x = 64 -> 16384
    int o = i >> 7;
    int k = i & 127;
    wt[(size_t)m * 16384 + (size_t)k * 128 + o] = W[o * 128 + k];
}

// ---------------- mean aggregation: one wave per node, 4-deep load pipeline ----------------
__global__ void __launch_bounds__(256) agg_kernel(const float* __restrict__ x,
                                                  const int* __restrict__ row,
                                                  const int* __restrict__ cnt,
                                                  const int* __restrict__ es,
                                                  float* __restrict__ mean,
                                                  int nodebase) {
    int wave = (blockIdx.x * 256 + threadIdx.x) >> 6;
    int lane = threadIdx.x & 63;
    if (wave >= N_NODES) return;
    int gi = nodebase + wave;
    int start = row[gi];
    int deg = cnt[gi];
    float ax = 0.f, ay = 0.f;
    for (int c = 0; c < deg; c += 64) {
        int m = min(64, deg - c);
        int eid = (lane < m) ? es[start + c + lane] : 0;
        int j = 0;
        for (; j + 4 <= m; j += 4) {
            int s0 = __shfl(eid, j,     64);
            int s1 = __shfl(eid, j + 1, 64);
            int s2 = __shfl(eid, j + 2, 64);
            int s3 = __shfl(eid, j + 3, 64);
            float2 v0 = *reinterpret_cast<const float2*>(x + (size_t)s0 * 128 + lane * 2);
            float2 v1 = *reinterpret_cast<const float2*>(x + (size_t)s1 * 128 + lane * 2);
            float2 v2 = *reinterpret_cast<const float2*>(x + (size_t)s2 * 128 + lane * 2);
            float2 v3 = *reinterpret_cast<const float2*>(x + (size_t)s3 * 128 + lane * 2);
            ax += v0.x + v1.x + v2.x + v3.x;
            ay += v0.y + v1.y + v2.y + v3.y;
        }
        for (; j < m; ++j) {
            int s = __shfl(eid, j, 64);
            float2 v = *reinterpret_cast<const float2*>(x + (size_t)s * 128 + lane * 2);
            ax += v.x; ay += v.y;
        }
    }
    float inv = 1.0f / fmaxf((float)deg, 1.0f);
    float2 o; o.x = ax * inv; o.y = ay * inv;
    *reinterpret_cast<float2*>(mean + (size_t)wave * 128 + lane * 2) = o;
}

// ---------------- fused double-GEMM: relu(mean@Wl^T + x@Wr^T + b) ----------------
// tile: 128 nodes x 64 outs, 256 threads, micro 8x4. LDS ~50 KB -> 3 blocks/CU.
#define TM 128
#define TO 64
#define KC 32
#define ASTR 34          // a_lds row stride (pad 2)
#define BSTR 66          // b_lds row stride (pad 2)

__global__ void __launch_bounds__(256) gemm_kernel(const float* __restrict__ Am,
                                                   const float* __restrict__ Ax,
                                                   const float* __restrict__ BTl,
                                                   const float* __restrict__ BTr,
                                                   const float* __restrict__ bias,
                                                   float* __restrict__ outBuf,
                                                   float* __restrict__ pool,
                                                   const int* __restrict__ batch,
                                                   int poolBase) {
    __shared__ float b_lds[128 * BSTR];   // 33 KB
    __shared__ float a_lds[TM * ASTR];    // 17 KB
    int tid = threadIdx.x;
    int node0 = blockIdx.x * TM;
    int ocol0 = blockIdx.y * TO;

    int og = tid & 15;
    int ng = tid >> 4;
    int oc = og * 4;
    int nr = ng * 8;

    float acc[8][4];
    #pragma unroll
    for (int n = 0; n < 8; ++n)
        #pragma unroll
        for (int j = 0; j < 4; ++j) acc[n][j] = 0.f;

    for (int phase = 0; phase < 2; ++phase) {
        const float* A  = phase ? Ax  : Am;
        const float* BT = phase ? BTr : BTl;
        __syncthreads();
        // stage B full tile [128 k][64 o]
        {
            int k = tid & 127;
            int oh = tid >> 7;
            const float* src = BT + (size_t)k * 128 + ocol0 + oh * 32;
            float* dst = &b_lds[k * BSTR + oh * 32];
            #pragma unroll
            for (int j = 0; j < 8; ++j) {
                float4 v = reinterpret_cast<const float4*>(src)[j];
                float2* d2 = reinterpret_cast<float2*>(dst + j * 4);
                d2[0] = make_float2(v.x, v.y);
                d2[1] = make_float2(v.z, v.w);
            }
        }
        for (int kc = 0; kc < 128; kc += KC) {
            if (kc) __syncthreads();
            // stage A chunk [128 nodes][32 k]
            {
                int nloc = tid >> 1;
                int kk0 = (tid & 1) * 16;
                int gnode = node0 + nloc;
                const float* src = A + (size_t)gnode * 128 + kc + kk0;
                float* dst = &a_lds[nloc * ASTR + kk0];
                #pragma unroll
                for (int j = 0; j < 4; ++j) {
                    float4 v = (gnode < N_NODES) ? reinterpret_cast<const float4*>(src)[j]
                                                 : make_float4(0.f, 0.f, 0.f, 0.f);
                    float2* d2 = reinterpret_cast<float2*>(dst + j * 4);
                    d2[0] = make_float2(v.x, v.y);
                    d2[1] = make_float2(v.z, v.w);
                }
            }
            __syncthreads();
            #pragma unroll
            for (int kk = 0; kk < KC; kk += 2) {
                // BUGFIX (round 2): B row index must be kc+kk, not kk.
                const float* br0 = &b_lds[(kc + kk) * BSTR];
                const float* br1 = &b_lds[(kc + kk + 1) * BSTR];
                float2 b0a = *reinterpret_cast<const float2*>(br0 + oc);
                float2 b0b = *reinterpret_cast<const float2*>(br0 + oc + 2);
                float2 b1a = *reinterpret_cast<const float2*>(br1 + oc);
                float2 b1b = *reinterpret_cast<const float2*>(br1 + oc + 2);
                #pragma unroll
                for (int n = 0; n < 8; ++n) {
                    float2 a = *reinterpret_cast<const float2*>(&a_lds[(nr + n) * ASTR + kk]);
                    acc[n][0] += a.x * b0a.x + a.y * b1a.x;
                    acc[n][1] += a.x * b0a.y + a.y * b1a.y;
                    acc[n][2] += a.x * b0b.x + a.y * b1b.x;
                    acc[n][3] += a.x * b0b.y + a.y * b1b.y;
                }
            }
        }
    }

    float4 bia = *reinterpret_cast<const float4*>(&bias[ocol0 + oc]);
    if (outBuf) {
        #pragma unroll
        for (int n = 0; n < 8; ++n) {
            int node = node0 + nr + n;
            if (node < N_NODES) {
                float4 r;
                r.x = fmaxf(acc[n][0] + bia.x, 0.f);
                r.y = fmaxf(acc[n][1] + bia.y, 0.f);
                r.z = fmaxf(acc[n][2] + bia.z, 0.f);
                r.w = fmaxf(acc[n][3] + bia.w, 0.f);
                *reinterpret_cast<float4*>(&outBuf[(size_t)node * 128 + ocol0 + oc]) = r;
            }
        }
    } else {
        // relu + fused global_add_pool (batch sorted -> run-length accumulate)
        int curg = -1;
        float r0 = 0.f, r1 = 0.f, r2 = 0.f, r3 = 0.f;
        for (int n = 0; n < 8; ++n) {
            int node = node0 + nr + n;
            if (node >= N_NODES) break;
            int g = batch[node];
            float v0 = fmaxf(acc[n][0] + bia.x, 0.f);
            float v1 = fmaxf(acc[n][1] + bia.y, 0.f);
            float v2 = fmaxf(acc[n][2] + bia.z, 0.f);
            float v3 = fmaxf(acc[n][3] + bia.w, 0.f);
            if (g != curg) {
                if (curg >= 0) {
                    float* p = &pool[(size_t)curg * 256 + poolBase + ocol0 + oc];
                    atomicAdd(p + 0, r0); atomicAdd(p + 1, r1);
                    atomicAdd(p + 2, r2); atomicAdd(p + 3, r3);
                }
                curg = g; r0 = v0; r1 = v1; r2 = v2; r3 = v3;
            } else { r0 += v0; r1 += v1; r2 += v2; r3 += v3; }
        }
        if (curg >= 0) {
            float* p = &pool[(size_t)curg * 256 + poolBase + ocol0 + oc];
            atomicAdd(p + 0, r0); atomicAdd(p + 1, r1);
            atomicAdd(p + 2, r2); atomicAdd(p + 3, r3);
        }
    }
}

// ---------------- MLP head + log_softmax, one block per graph ----------------
__global__ void __launch_bounds__(128) head_kernel(const float* __restrict__ pool,
                                                   const float* __restrict__ W1, const float* __restrict__ bh1,
                                                   const float* __restrict__ W2, const float* __restrict__ bh2,
                                                   const float* __restrict__ W3, const float* __restrict__ bh3,
                                                   float* __restrict__ out) {
    __shared__ float xg[256];
    __shared__ float h1[128];
    __shared__ float h2[64];
    __shared__ float lg[2];
    int g = blockIdx.x, t = threadIdx.x;
    xg[t] = pool[(size_t)g * 256 + t];
    xg[t + 128] = pool[(size_t)g * 256 + 128 + t];
    __syncthreads();
    float s = bh1[t];
    for (int k = 0; k < 256; ++k) s += W1[t * 256 + k] * xg[k];
    h1[t] = fmaxf(s, 0.f);
    __syncthreads();
    if (t < 64) {
        float s2 = bh2[t];
        for (int k = 0; k < 128; ++k) s2 += W2[t * 128 + k] * h1[k];
        h2[t] = fmaxf(s2, 0.f);
    }
    __syncthreads();
    if (t < 2) {
        float s3 = bh3[t];
        for (int k = 0; k < 64; ++k) s3 += W3[t * 64 + k] * h2[k];
        lg[t] = s3;
    }
    __syncthreads();
    if (t == 0) {
        float m = fmaxf(lg[0], lg[1]);
        float lse = m + logf(expf(lg[0] - m) + expf(lg[1] - m));
        out[g * 2 + 0] = lg[0] - lse;
        out[g * 2 + 1] = lg[1] - lse;
    }
}

extern "C" void kernel_launch(void* const* d_in, const int* in_sizes, int n_in,
                              void* d_out, int out_size, void* d_ws, size_t ws_size,
                              hipStream_t stream) {
    const float* sc_x = (const float*)d_in[0];
    const float* fc_x = (const float*)d_in[1];
    const int* sc_e   = (const int*)d_in[2];
    const int* fc_e   = (const int*)d_in[3];
    const int* batch  = (const int*)d_in[4];
    const float* sc_Wl1 = (const float*)d_in[5];
    const float* sc_Wr1 = (const float*)d_in[6];
    const float* sc_b1  = (const float*)d_in[7];
    const float* sc_Wl2 = (const float*)d_in[8];
    const float* sc_Wr2 = (const float*)d_in[9];
    const float* sc_b2  = (const float*)d_in[10];
    const float* fc_Wl1 = (const float*)d_in[11];
    const float* fc_Wr1 = (const float*)d_in[12];
    const float* fc_b1  = (const float*)d_in[13];
    const float* fc_Wl2 = (const float*)d_in[14];
    const float* fc_Wr2 = (const float*)d_in[15];
    const float* fc_b2  = (const float*)d_in[16];
    const float* W1  = (const float*)d_in[17];
    const float* bh1 = (const float*)d_in[18];
    const float* W2  = (const float*)d_in[19];
    const float* bh2 = (const float*)d_in[20];
    const float* W3  = (const float*)d_in[21];
    const float* bh3 = (const float*)d_in[22];

    int* iw   = (int*)d_ws;
    float* fw = (float*)d_ws;
    int* cnt   = iw + O_CNT;
    int* cur   = iw + O_CUR;
    float* pool = fw + O_POOL;
    int* row   = iw + O_ROW;
    int* bs    = iw + O_BS;
    int* es    = iw + O_ES;
    float* WT    = fw + O_WT;
    float* meanb = fw + O_MEAN;
    float* hb    = fw + O_H;

    hipMemsetAsync(d_ws, 0, ZERO_BYTES, stream);

    const int EB = (2 * E_EDGES + 255) / 256;
    hist_kernel<<<EB, 256, 0, stream>>>(sc_e + E_EDGES, fc_e + E_EDGES, cnt);

    const int NB = (2 * N_NODES + 255) / 256;   // 391
    scan_blocks<<<NB, 256, 0, stream>>>(cnt, row, bs, 2 * N_NODES);
    scan_sums<<<1, 512, 0, stream>>>(bs, NB);
    scan_add<<<NB, 256, 0, stream>>>(row, bs, 2 * N_NODES);
    scatter_kernel<<<EB, 256, 0, stream>>>(sc_e, fc_e, row, cur, es);

    transpose_weights<<<dim3(64, 8), 256, 0, stream>>>(sc_Wl1, sc_Wr1, sc_Wl2, sc_Wr2,
                                                       fc_Wl1, fc_Wr1, fc_Wl2, fc_Wr2, WT);

    const int AGB = (N_NODES + 3) / 4;          // 12500 blocks, 4 waves each
    dim3 gg((N_NODES + TM - 1) / TM, 2);        // (391, 2)

    // SC branch
    agg_kernel<<<AGB, 256, 0, stream>>>(sc_x, row, cnt, es, meanb, 0);
    gemm_kernel<<<gg, 256, 0, stream>>>(meanb, sc_x, WT + 0 * 16384, WT + 1 * 16384, sc_b1,
                                        hb, nullptr, nullptr, 0);
    agg_kernel<<<AGB, 256, 0, stream>>>(hb, row, cnt, es, meanb, 0);
    gemm_kernel<<<gg, 256, 0, stream>>>(meanb, hb, WT + 2 * 16384, WT + 3 * 16384, sc_b2,
                                        nullptr, pool, batch, 0);
    // FC branch
    agg_kernel<<<AGB, 256, 0, stream>>>(fc_x, row, cnt, es, meanb, N_NODES);
    gemm_kernel<<<gg, 256, 0, stream>>>(meanb, fc_x, WT + 4 * 16384, WT + 5 * 16384, fc_b1,
                                        hb, nullptr, nullptr, 0);
    agg_kernel<<<AGB, 256, 0, stream>>>(hb, row, cnt, es, meanb, N_NODES);
    gemm_kernel<<<gg, 256, 0, stream>>>(meanb, hb, WT + 6 * 16384, WT + 7 * 16384, fc_b2,
                                        nullptr, pool, batch, 128);

    head_kernel<<<G_GRAPHS, 128, 0, stream>>>(pool, W1, bh1, W2, bh2, W3, bh3, (float*)d_out);
}

// Round 4
// 508.333 us; speedup vs baseline: 1.8072x; 1.8072x over previous
//
#include <hip/hip_runtime.h>
#include <hip/hip_bf16.h>

#define N_NODES 50000
#define E_EDGES 800000
#define G_GRAPHS 64

typedef __attribute__((ext_vector_type(8))) short s16x8;   // 8 bf16 (4 VGPRs)
typedef __attribute__((ext_vector_type(4))) float f32x4;   // MFMA acc

// ---------------- workspace layout (4-byte words) ----------------
constexpr size_t O_CNT  = 0;        // int[100000]   per-node in-degree (sc then fc)
constexpr size_t O_CUR  = 102400;   // int[100000]   scatter cursors
constexpr size_t O_POOL = 204800;   // float[16384]  [G][256] pooled (sc|fc)
constexpr size_t O_ROW  = 221184;   // int[100000]   CSR row starts (excl scan)
constexpr size_t O_BS   = 323584;   // int[512]      scan block sums
constexpr size_t O_ES   = 324608;   // int[1600000]  src ids sorted by dst
constexpr size_t O_WB   = 1924608;  // bf16[8*16384] weights (layout [m][o][k])
constexpr size_t O_XB   = 1990144;  // bf16[50000*128] x in bf16 (reused sc->fc)
constexpr size_t O_MEAN = 5190144;  // bf16[50000*128]
constexpr size_t O_HB   = 8390144;  // bf16[50000*128]
constexpr size_t ZERO_BYTES = O_ROW * 4;   // cnt + cursor + pool zeroed

__device__ __forceinline__ unsigned short f2bf(float f) {
    __hip_bfloat16 h = __float2bfloat16(f);
    return *reinterpret_cast<unsigned short*>(&h);
}
__device__ __forceinline__ float bflo(unsigned int v) { return __uint_as_float(v << 16); }
__device__ __forceinline__ float bfhi(unsigned int v) { return __uint_as_float(v & 0xffff0000u); }

// ---------------- CSR build ----------------
__global__ void hist_kernel(const int* __restrict__ sc_dst, const int* __restrict__ fc_dst,
                            int* __restrict__ cnt) {
    int e = blockIdx.x * blockDim.x + threadIdx.x;
    if (e < E_EDGES) atomicAdd(&cnt[sc_dst[e]], 1);
    else if (e < 2 * E_EDGES) atomicAdd(&cnt[N_NODES + fc_dst[e - E_EDGES]], 1);
}

__global__ void scan_blocks(const int* __restrict__ cnt, int* __restrict__ exsc,
                            int* __restrict__ bsums, int n) {
    __shared__ int wsum[8];
    int i = blockIdx.x * 256 + threadIdx.x;
    int v = (i < n) ? cnt[i] : 0;
    int lane = threadIdx.x & 63;
    int incl = v;
    #pragma unroll
    for (int d = 1; d < 64; d <<= 1) {
        int t = __shfl_up(incl, d, 64);
        if (lane >= d) incl += t;
    }
    int wid = threadIdx.x >> 6;
    if (lane == 63) wsum[wid] = incl;
    __syncthreads();
    int pre = 0;
    for (int w = 0; w < wid; ++w) pre += wsum[w];
    incl += pre;
    if (i < n) exsc[i] = incl - v;
    if (threadIdx.x == 255) bsums[blockIdx.x] = incl;
}

__global__ void scan_sums(int* __restrict__ bsums, int nb) {
    __shared__ int wsum[8];
    int t = threadIdx.x;          // 512 threads
    int v = (t < nb) ? bsums[t] : 0;
    int lane = t & 63;
    int incl = v;
    #pragma unroll
    for (int d = 1; d < 64; d <<= 1) {
        int u = __shfl_up(incl, d, 64);
        if (lane >= d) incl += u;
    }
    int wid = t >> 6;
    if (lane == 63) wsum[wid] = incl;
    __syncthreads();
    int pre = 0;
    for (int w = 0; w < wid; ++w) pre += wsum[w];
    incl += pre;
    bsums[t] = incl - v;          // exclusive, in place
}

__global__ void scan_add(int* __restrict__ exsc, const int* __restrict__ boffs, int n) {
    int i = blockIdx.x * 256 + threadIdx.x;
    if (i < n) exsc[i] += boffs[blockIdx.x];
}

__global__ void scatter_kernel(const int* __restrict__ sc_e, const int* __restrict__ fc_e,
                               const int* __restrict__ row, int* __restrict__ cur,
                               int* __restrict__ es) {
    int e = blockIdx.x * blockDim.x + threadIdx.x;
    if (e < E_EDGES) {
        int src = sc_e[e];
        int dst = sc_e[E_EDGES + e];
        int pos = atomicAdd(&cur[dst], 1);
        es[row[dst] + pos] = src;
    } else if (e < 2 * E_EDGES) {
        int ee = e - E_EDGES;
        int src = fc_e[ee];
        int dst = fc_e[E_EDGES + ee];
        int pos = atomicAdd(&cur[N_NODES + dst], 1);
        es[row[N_NODES + dst] + pos] = src;
    }
}

// ---------------- weight convert fp32 -> bf16, layout kept [o][k] ----------------
__global__ void cvt_w_kernel(const float* w0, const float* w1, const float* w2, const float* w3,
                             const float* w4, const float* w5, const float* w6, const float* w7,
                             unsigned short* __restrict__ wb) {
    const float* W;
    int m = blockIdx.y;
    switch (m) {
        case 0: W = w0; break; case 1: W = w1; break;
        case 2: W = w2; break; case 3: W = w3; break;
        case 4: W = w4; break; case 5: W = w5; break;
        case 6: W = w6; break; default: W = w7; break;
    }
    int i = blockIdx.x * 256 + threadIdx.x;   // grid.x = 64 -> 16384
    wb[(size_t)m * 16384 + i] = f2bf(W[i]);
}

// ---------------- feature convert fp32 -> bf16 (8 elems / thread) ----------------
__global__ void cvt_x_kernel(const float* __restrict__ src, unsigned short* __restrict__ dst) {
    int i = blockIdx.x * 256 + threadIdx.x;   // 800000 groups of 8
    if (i >= (N_NODES * 128) / 8) return;
    const float4* s = reinterpret_cast<const float4*>(src) + (size_t)i * 2;
    float4 a = s[0], b = s[1];
    union { s16x8 v; unsigned short u[8]; } p;
    p.u[0] = f2bf(a.x); p.u[1] = f2bf(a.y); p.u[2] = f2bf(a.z); p.u[3] = f2bf(a.w);
    p.u[4] = f2bf(b.x); p.u[5] = f2bf(b.y); p.u[6] = f2bf(b.z); p.u[7] = f2bf(b.w);
    reinterpret_cast<s16x8*>(dst)[i] = p.v;
}

// ---------------- mean aggregation (bf16 in/out): one wave per node ----------------
__global__ void __launch_bounds__(256) agg_kernel(const unsigned short* __restrict__ x,
                                                  const int* __restrict__ row,
                                                  const int* __restrict__ cnt,
                                                  const int* __restrict__ es,
                                                  unsigned short* __restrict__ mean,
                                                  int nodebase) {
    int wave = (blockIdx.x * 256 + threadIdx.x) >> 6;
    int lane = threadIdx.x & 63;
    if (wave >= N_NODES) return;
    int gi = nodebase + wave;
    int start = row[gi];
    int deg = cnt[gi];
    float ax = 0.f, ay = 0.f;
    for (int c = 0; c < deg; c += 64) {
        int m = min(64, deg - c);
        int eid = (lane < m) ? es[start + c + lane] : 0;
        int j = 0;
        for (; j + 4 <= m; j += 4) {
            int s0 = __shfl(eid, j,     64);
            int s1 = __shfl(eid, j + 1, 64);
            int s2 = __shfl(eid, j + 2, 64);
            int s3 = __shfl(eid, j + 3, 64);
            unsigned int v0 = *reinterpret_cast<const unsigned int*>(x + (size_t)s0 * 128 + lane * 2);
            unsigned int v1 = *reinterpret_cast<const unsigned int*>(x + (size_t)s1 * 128 + lane * 2);
            unsigned int v2 = *reinterpret_cast<const unsigned int*>(x + (size_t)s2 * 128 + lane * 2);
            unsigned int v3 = *reinterpret_cast<const unsigned int*>(x + (size_t)s3 * 128 + lane * 2);
            ax += bflo(v0) + bflo(v1) + bflo(v2) + bflo(v3);
            ay += bfhi(v0) + bfhi(v1) + bfhi(v2) + bfhi(v3);
        }
        for (; j < m; ++j) {
            int s = __shfl(eid, j, 64);
            unsigned int v = *reinterpret_cast<const unsigned int*>(x + (size_t)s * 128 + lane * 2);
            ax += bflo(v); ay += bfhi(v);
        }
    }
    float inv = 1.0f / fmaxf((float)deg, 1.0f);
    unsigned int r = (unsigned int)f2bf(ax * inv) | ((unsigned int)f2bf(ay * inv) << 16);
    *reinterpret_cast<unsigned int*>(mean + (size_t)wave * 128 + lane * 2) = r;
}

// ---------------- MFMA GEMM: relu([mean|x] @ [Wl;Wr]^T + b), K=256 fused ----------------
// tile 64 nodes x 128 cols; 4 waves, each 32x64 (2x4 frags of 16x16); BK=32, 8 k-steps.
// LDS 24 KB double-buffered; XOR slot swizzle (2-way max bank aliasing).
__global__ void __launch_bounds__(256) gemm_mfma(const unsigned short* __restrict__ Am,
                                                 const unsigned short* __restrict__ Ax,
                                                 const unsigned short* __restrict__ Bl,
                                                 const unsigned short* __restrict__ Br,
                                                 const float* __restrict__ bias,
                                                 unsigned short* __restrict__ outH,
                                                 float* __restrict__ pool,
                                                 const int* __restrict__ batch,
                                                 int poolBase) {
    __shared__ s16x8 lds_a[2][256];   // [64 rows][4 slots of 8 bf16]
    __shared__ s16x8 lds_b[2][512];   // [128 rows][4 slots]

    const int tid = threadIdx.x;
    const int lane = tid & 63;
    const int w = tid >> 6;
    const int node0 = blockIdx.x * 64;

    const int wr = w >> 1;            // row half (32 rows)
    const int wc = w & 1;             // col half (64 cols)
    const int fr = lane & 15;
    const int fg = lane >> 4;

    f32x4 acc[2][4];
    #pragma unroll
    for (int mf = 0; mf < 2; ++mf)
        #pragma unroll
        for (int nf = 0; nf < 4; ++nf) acc[mf][nf] = (f32x4){0.f, 0.f, 0.f, 0.f};

    // staging: thread t fills LDS entry t (row = t>>2, slot = t&3); the data placed at
    // slot s is k-group g = s ^ ((row>>1)&3)  (XOR swizzle, matched on read)
    const int sa_row = tid >> 2, sa_slot = tid & 3;
    const int sa_g = sa_slot ^ ((sa_row >> 1) & 3);
    const size_t a_off = (size_t)min(node0 + sa_row, N_NODES - 1) * 128 + sa_g * 8;
    const int sb_row0 = tid >> 2;
    const size_t b_off0 = (size_t)sb_row0 * 128 + (sa_slot ^ ((sb_row0 >> 1) & 3)) * 8;
    const int sb_row1 = 64 + (tid >> 2);
    const size_t b_off1 = (size_t)sb_row1 * 128 + (sa_slot ^ ((sb_row1 >> 1) & 3)) * 8;

    // fragment read indices (swizzled)
    const int arow0 = wr * 32 + fr;
    const int arow1 = arow0 + 16;
    const int aidx0 = arow0 * 4 + (fg ^ ((arow0 >> 1) & 3));
    const int aidx1 = arow1 * 4 + (fg ^ ((arow1 >> 1) & 3));
    int bidx[4];
    #pragma unroll
    for (int nf = 0; nf < 4; ++nf) {
        int br = wc * 64 + nf * 16 + fr;
        bidx[nf] = br * 4 + (fg ^ ((br >> 1) & 3));
    }

    // k-step kc in [0,8): kc<4 -> (Am, Bl) else (Ax, Br); local k offset (kc&3)*32 elems
    #define LOAD_A(kc) (*reinterpret_cast<const s16x8*>(((kc) < 4 ? Am : Ax) + (((kc) & 3) * 32) + a_off))
    #define LOAD_B0(kc) (*reinterpret_cast<const s16x8*>(((kc) < 4 ? Bl : Br) + (((kc) & 3) * 32) + b_off0))
    #define LOAD_B1(kc) (*reinterpret_cast<const s16x8*>(((kc) < 4 ? Bl : Br) + (((kc) & 3) * 32) + b_off1))

    {
        s16x8 ra = LOAD_A(0), rb0 = LOAD_B0(0), rb1 = LOAD_B1(0);
        lds_a[0][tid] = ra; lds_b[0][tid] = rb0; lds_b[0][256 + tid] = rb1;
    }
    __syncthreads();

    #pragma unroll
    for (int kc = 0; kc < 8; ++kc) {
        const int cur = kc & 1;
        s16x8 ra, rb0, rb1;
        if (kc < 7) { ra = LOAD_A(kc + 1); rb0 = LOAD_B0(kc + 1); rb1 = LOAD_B1(kc + 1); }
        s16x8 a0 = lds_a[cur][aidx0];
        s16x8 a1 = lds_a[cur][aidx1];
        #pragma unroll
        for (int nf = 0; nf < 4; ++nf) {
            s16x8 bv = lds_b[cur][bidx[nf]];
            acc[0][nf] = __builtin_amdgcn_mfma_f32_16x16x32_bf16(a0, bv, acc[0][nf], 0, 0, 0);
            acc[1][nf] = __builtin_amdgcn_mfma_f32_16x16x32_bf16(a1, bv, acc[1][nf], 0, 0, 0);
        }
        if (kc < 7) { lds_a[cur ^ 1][tid] = ra; lds_b[cur ^ 1][tid] = rb0; lds_b[cur ^ 1][256 + tid] = rb1; }
        __syncthreads();
    }
    #undef LOAD_A
    #undef LOAD_B0
    #undef LOAD_B1

    // C/D layout (HW-verified): col = lane&15, row = (lane>>4)*4 + reg
    if (outH) {
        #pragma unroll
        for (int mf = 0; mf < 2; ++mf)
            #pragma unroll
            for (int nf = 0; nf < 4; ++nf) {
                int col = wc * 64 + nf * 16 + fr;
                float bv = bias[col];
                #pragma unroll
                for (int r = 0; r < 4; ++r) {
                    int node = node0 + wr * 32 + mf * 16 + fg * 4 + r;
                    if (node < N_NODES)
                        outH[(size_t)node * 128 + col] = f2bf(fmaxf(acc[mf][nf][r] + bv, 0.f));
                }
            }
    } else {
        int gids[2][4];
        #pragma unroll
        for (int mf = 0; mf < 2; ++mf)
            #pragma unroll
            for (int r = 0; r < 4; ++r) {
                int node = node0 + wr * 32 + mf * 16 + fg * 4 + r;
                gids[mf][r] = (node < N_NODES) ? batch[node] : -1;
            }
        #pragma unroll
        for (int nf = 0; nf < 4; ++nf) {
            int col = wc * 64 + nf * 16 + fr;
            float bv = bias[col];
            float* pbase = &pool[poolBase + col];
            int curg = -1; float s = 0.f;
            #pragma unroll
            for (int mf = 0; mf < 2; ++mf)
                #pragma unroll
                for (int r = 0; r < 4; ++r) {
                    int g = gids[mf][r];
                    if (g < 0) continue;
                    float v = fmaxf(acc[mf][nf][r] + bv, 0.f);
                    if (g != curg) {
                        if (curg >= 0) atomicAdd(pbase + (size_t)curg * 256, s);
                        curg = g; s = v;
                    } else s += v;
                }
            if (curg >= 0) atomicAdd(pbase + (size_t)curg * 256, s);
        }
    }
}

// ---------------- MLP head + log_softmax, one block per graph ----------------
__global__ void __launch_bounds__(128) head_kernel(const float* __restrict__ pool,
                                                   const float* __restrict__ W1, const float* __restrict__ bh1,
                                                   const float* __restrict__ W2, const float* __restrict__ bh2,
                                                   const float* __restrict__ W3, const float* __restrict__ bh3,
                                                   float* __restrict__ out) {
    __shared__ float xg[256];
    __shared__ float h1[128];
    __shared__ float h2[64];
    __shared__ float lg[2];
    int g = blockIdx.x, t = threadIdx.x;
    xg[t] = pool[(size_t)g * 256 + t];
    xg[t + 128] = pool[(size_t)g * 256 + 128 + t];
    __syncthreads();
    float s = bh1[t];
    for (int k = 0; k < 256; ++k) s += W1[t * 256 + k] * xg[k];
    h1[t] = fmaxf(s, 0.f);
    __syncthreads();
    if (t < 64) {
        float s2 = bh2[t];
        for (int k = 0; k < 128; ++k) s2 += W2[t * 128 + k] * h1[k];
        h2[t] = fmaxf(s2, 0.f);
    }
    __syncthreads();
    if (t < 2) {
        float s3 = bh3[t];
        for (int k = 0; k < 64; ++k) s3 += W3[t * 64 + k] * h2[k];
        lg[t] = s3;
    }
    __syncthreads();
    if (t == 0) {
        float m = fmaxf(lg[0], lg[1]);
        float lse = m + logf(expf(lg[0] - m) + expf(lg[1] - m));
        out[g * 2 + 0] = lg[0] - lse;
        out[g * 2 + 1] = lg[1] - lse;
    }
}

extern "C" void kernel_launch(void* const* d_in, const int* in_sizes, int n_in,
                              void* d_out, int out_size, void* d_ws, size_t ws_size,
                              hipStream_t stream) {
    const float* sc_x = (const float*)d_in[0];
    const float* fc_x = (const float*)d_in[1];
    const int* sc_e   = (const int*)d_in[2];
    const int* fc_e   = (const int*)d_in[3];
    const int* batch  = (const int*)d_in[4];
    const float* sc_Wl1 = (const float*)d_in[5];
    const float* sc_Wr1 = (const float*)d_in[6];
    const float* sc_b1  = (const float*)d_in[7];
    const float* sc_Wl2 = (const float*)d_in[8];
    const float* sc_Wr2 = (const float*)d_in[9];
    const float* sc_b2  = (const float*)d_in[10];
    const float* fc_Wl1 = (const float*)d_in[11];
    const float* fc_Wr1 = (const float*)d_in[12];
    const float* fc_b1  = (const float*)d_in[13];
    const float* fc_Wl2 = (const float*)d_in[14];
    const float* fc_Wr2 = (const float*)d_in[15];
    const float* fc_b2  = (const float*)d_in[16];
    const float* W1  = (const float*)d_in[17];
    const float* bh1 = (const float*)d_in[18];
    const float* W2  = (const float*)d_in[19];
    const float* bh2 = (const float*)d_in[20];
    const float* W3  = (const float*)d_in[21];
    const float* bh3 = (const float*)d_in[22];

    int* iw = (int*)d_ws;
    float* fw = (float*)d_ws;
    int* cnt = iw + O_CNT;
    int* cur = iw + O_CUR;
    float* pool = fw + O_POOL;
    int* row = iw + O_ROW;
    int* bs  = iw + O_BS;
    int* es  = iw + O_ES;
    unsigned short* WB    = (unsigned short*)(iw + O_WB);
    unsigned short* xb    = (unsigned short*)(iw + O_XB);
    unsigned short* meanb = (unsigned short*)(iw + O_MEAN);
    unsigned short* hb    = (unsigned short*)(iw + O_HB);

    hipMemsetAsync(d_ws, 0, ZERO_BYTES, stream);

    const int EB = (2 * E_EDGES + 255) / 256;
    hist_kernel<<<EB, 256, 0, stream>>>(sc_e + E_EDGES, fc_e + E_EDGES, cnt);

    const int NB = (2 * N_NODES + 255) / 256;   // 391
    scan_blocks<<<NB, 256, 0, stream>>>(cnt, row, bs, 2 * N_NODES);
    scan_sums<<<1, 512, 0, stream>>>(bs, NB);
    scan_add<<<NB, 256, 0, stream>>>(row, bs, 2 * N_NODES);
    scatter_kernel<<<EB, 256, 0, stream>>>(sc_e, fc_e, row, cur, es);

    cvt_w_kernel<<<dim3(64, 8), 256, 0, stream>>>(sc_Wl1, sc_Wr1, sc_Wl2, sc_Wr2,
                                                  fc_Wl1, fc_Wr1, fc_Wl2, fc_Wr2, WB);

    const int AGB = (N_NODES + 3) / 4;          // 12500 blocks
    const int CVB = ((N_NODES * 128) / 8 + 255) / 256;  // 3125
    const int GGB = (N_NODES + 63) / 64;        // 782

    // SC branch
    cvt_x_kernel<<<CVB, 256, 0, stream>>>(sc_x, xb);
    agg_kernel<<<AGB, 256, 0, stream>>>(xb, row, cnt, es, meanb, 0);
    gemm_mfma<<<GGB, 256, 0, stream>>>(meanb, xb, WB + 0 * 16384, WB + 1 * 16384, sc_b1,
                                       hb, nullptr, nullptr, 0);
    agg_kernel<<<AGB, 256, 0, stream>>>(hb, row, cnt, es, meanb, 0);
    gemm_mfma<<<GGB, 256, 0, stream>>>(meanb, hb, WB + 2 * 16384, WB + 3 * 16384, sc_b2,
                                       nullptr, pool, batch, 0);
    // FC branch
    cvt_x_kernel<<<CVB, 256, 0, stream>>>(fc_x, xb);
    agg_kernel<<<AGB, 256, 0, stream>>>(xb, row, cnt, es, meanb, N_NODES);
    gemm_mfma<<<GGB, 256, 0, stream>>>(meanb, xb, WB + 4 * 16384, WB + 5 * 16384, fc_b1,
                                       hb, nullptr, nullptr, 0);
    agg_kernel<<<AGB, 256, 0, stream>>>(hb, row, cnt, es, meanb, N_NODES);
    gemm_mfma<<<GGB, 256, 0, stream>>>(meanb, hb, WB + 6 * 16384, WB + 7 * 16384, fc_b2,
                                       nullptr, pool, batch, 128);

    head_kernel<<<G_GRAPHS, 128, 0, stream>>>(pool, W1, bh1, W2, bh2, W3, bh3, (float*)d_out);
}

// Round 5
// 390.829 us; speedup vs baseline: 2.3505x; 1.3007x over previous
//
#include <hip/hip_runtime.h>
#include <hip/hip_bf16.h>

#define N_NODES 50000
#define E_EDGES 800000
#define G_GRAPHS 64
#define NBUCK 392            // 2 sets * 196 buckets of 256 nodes
#define BCAP 5120            // per-bucket capacity (mean 4096, sigma 64)

typedef __attribute__((ext_vector_type(8))) short s16x8;   // 8 bf16 (4 VGPRs)
typedef __attribute__((ext_vector_type(4))) float f32x4;   // MFMA acc

// ---------------- workspace layout (4-byte words) ----------------
constexpr size_t O_POOL   = 0;        // float[16384]  [G][256] pooled (sc|fc)
constexpr size_t O_GCUR   = 16384;    // int[512]      bucket fill cursors
constexpr size_t O_BSTART = 16896;    // int[512]      bucket start offsets (excl scan)
constexpr size_t O_ROW    = 17408;    // int[100000]   CSR row starts
constexpr size_t O_CNT    = 117408;   // int[100000]   per-node in-degree
constexpr size_t O_ES     = 217408;   // int[1600000]  src ids sorted by dst
constexpr size_t O_WB     = 1817408;  // bf16[8*16384] weights [m][o][k]
constexpr size_t O_XB     = 1882944;  // bf16[50000*128]
constexpr size_t O_MEAN   = 5082944;  // bf16[50000*128]; aliased as bucket buf during CSR build
constexpr size_t O_HB     = 8282944;  // bf16[50000*128]
constexpr size_t ZERO_BYTES = (16384 + 512) * 4;   // pool + gcur

__device__ __forceinline__ unsigned short f2bf(float f) {
    __hip_bfloat16 h = __float2bfloat16(f);
    return *reinterpret_cast<unsigned short*>(&h);
}
__device__ __forceinline__ float bflo(unsigned int v) { return __uint_as_float(v << 16); }
__device__ __forceinline__ float bfhi(unsigned int v) { return __uint_as_float(v & 0xffff0000u); }

// ---------------- pass 1: bin edges into 392 dst-range buckets ----------------
// tile 4096 edges/block, 512 threads; LDS counting-sort by bucket; coalesced flush.
__global__ void __launch_bounds__(512) bin_pass1(const int* __restrict__ sc_e,
                                                 const int* __restrict__ fc_e,
                                                 int* __restrict__ gcur,
                                                 unsigned int* __restrict__ buf) {
    __shared__ int hcnt[512];
    __shared__ int hexcl[512];
    __shared__ int hcur[512];
    __shared__ int gbase[512];
    __shared__ int wsum[8];
    __shared__ unsigned int stage[4096];

    const int tid = threadIdx.x;
    const int lane = tid & 63;
    const int wid = tid >> 6;
    const int tile0 = blockIdx.x * 4096;

    hcnt[tid] = 0;
    __syncthreads();

    int eb[8];
    unsigned int pk[8];
    #pragma unroll
    for (int j = 0; j < 8; ++j) {
        int ec = tile0 + j * 512 + tid;
        if (ec < 2 * E_EDGES) {
            int set = (ec >= E_EDGES);
            int local = ec - set * E_EDGES;
            const int* ep = set ? fc_e : sc_e;
            int src = ep[local];
            int dst = ep[E_EDGES + local];
            eb[j] = set * 196 + (dst >> 8);
            pk[j] = ((unsigned int)(dst & 255) << 16) | (unsigned int)src;
            atomicAdd(&hcnt[eb[j]], 1);
        } else eb[j] = -1;
    }
    __syncthreads();

    // exclusive scan of hcnt[512]
    {
        int v = hcnt[tid];
        int incl = v;
        #pragma unroll
        for (int d = 1; d < 64; d <<= 1) {
            int u = __shfl_up(incl, d, 64);
            if (lane >= d) incl += u;
        }
        if (lane == 63) wsum[wid] = incl;
        __syncthreads();
        int pre = 0;
        for (int w = 0; w < wid; ++w) pre += wsum[w];
        int excl = incl - v + pre;
        hexcl[tid] = excl;
        hcur[tid] = excl;
    }
    __syncthreads();

    // claim global bucket space
    if (tid < NBUCK) {
        int c = hcnt[tid];
        gbase[tid] = c ? atomicAdd(&gcur[tid], c) : 0;
    }

    // place packed edges into LDS sorted-by-bucket
    #pragma unroll
    for (int j = 0; j < 8; ++j) {
        if (eb[j] >= 0) {
            int pos = atomicAdd(&hcur[eb[j]], 1);
            stage[pos] = pk[j];
        }
    }
    __syncthreads();

    // flush bucket runs (coalesced-ish)
    for (int b = wid; b < NBUCK; b += 8) {
        int c = hcnt[b];
        if (!c) continue;
        int s = hexcl[b];
        int g0 = gbase[b];
        for (int i = lane; i < c; i += 64) {
            int gi = g0 + i;
            if (gi < BCAP) buf[(size_t)b * BCAP + gi] = stage[s + i];
        }
    }
}

// ---------------- tiny exclusive scan over bucket sizes ----------------
__global__ void bstart_scan(const int* __restrict__ gcur, int* __restrict__ bstart) {
    __shared__ int wsum[8];
    int t = threadIdx.x;          // 512
    int lane = t & 63, wid = t >> 6;
    int v = (t < NBUCK) ? min(gcur[t], BCAP) : 0;
    int incl = v;
    #pragma unroll
    for (int d = 1; d < 64; d <<= 1) {
        int u = __shfl_up(incl, d, 64);
        if (lane >= d) incl += u;
    }
    if (lane == 63) wsum[wid] = incl;
    __syncthreads();
    int pre = 0;
    for (int w = 0; w < wid; ++w) pre += wsum[w];
    if (t < NBUCK) bstart[t] = incl - v + pre;
}

// ---------------- pass 2: per-bucket counting sort -> es, cnt, row ----------------
__global__ void __launch_bounds__(256) bin_pass2(const unsigned int* __restrict__ buf,
                                                 const int* __restrict__ gcur,
                                                 const int* __restrict__ bstart,
                                                 int* __restrict__ row,
                                                 int* __restrict__ cnt,
                                                 int* __restrict__ es) {
    __shared__ int cntl[256];
    __shared__ int pexcl[256];
    __shared__ int pcur[256];
    __shared__ int wsum[4];
    __shared__ int stage[BCAP];

    const int b = blockIdx.x;
    const int tid = threadIdx.x;
    const int lane = tid & 63, wid = tid >> 6;
    const int sz = min(gcur[b], BCAP);
    const unsigned int* mybuf = buf + (size_t)b * BCAP;
    const int n0 = (b % 196) * 256;
    const int setbase = (b / 196) * N_NODES;

    cntl[tid] = 0;
    __syncthreads();
    for (int i = tid; i < sz; i += 256)
        atomicAdd(&cntl[mybuf[i] >> 16], 1);
    __syncthreads();
    {
        int v = cntl[tid];
        int incl = v;
        #pragma unroll
        for (int d = 1; d < 64; d <<= 1) {
            int u = __shfl_up(incl, d, 64);
            if (lane >= d) incl += u;
        }
        if (lane == 63) wsum[wid] = incl;
        __syncthreads();
        int pre = 0;
        for (int w = 0; w < wid; ++w) pre += wsum[w];
        int excl = incl - v + pre;
        pexcl[tid] = excl;
        pcur[tid] = excl;
    }
    __syncthreads();
    for (int i = tid; i < sz; i += 256) {
        unsigned int p = mybuf[i];
        int pos = atomicAdd(&pcur[p >> 16], 1);
        stage[pos] = (int)(p & 0xFFFFu);
    }
    __syncthreads();
    const int base = bstart[b];
    for (int i = tid; i < sz; i += 256) es[base + i] = stage[i];
    int node = n0 + tid;
    if (node < N_NODES) {
        cnt[setbase + node] = cntl[tid];
        row[setbase + node] = base + pexcl[tid];
    }
}

// ---------------- weight convert fp32 -> bf16, layout kept [o][k] ----------------
__global__ void cvt_w_kernel(const float* w0, const float* w1, const float* w2, const float* w3,
                             const float* w4, const float* w5, const float* w6, const float* w7,
                             unsigned short* __restrict__ wb) {
    const float* W;
    int m = blockIdx.y;
    switch (m) {
        case 0: W = w0; break; case 1: W = w1; break;
        case 2: W = w2; break; case 3: W = w3; break;
        case 4: W = w4; break; case 5: W = w5; break;
        case 6: W = w6; break; default: W = w7; break;
    }
    int i = blockIdx.x * 256 + threadIdx.x;   // grid.x = 64 -> 16384
    wb[(size_t)m * 16384 + i] = f2bf(W[i]);
}

// ---------------- feature convert fp32 -> bf16 (8 elems / thread) ----------------
__global__ void cvt_x_kernel(const float* __restrict__ src, unsigned short* __restrict__ dst) {
    int i = blockIdx.x * 256 + threadIdx.x;
    if (i >= (N_NODES * 128) / 8) return;
    const float4* s = reinterpret_cast<const float4*>(src) + (size_t)i * 2;
    float4 a = s[0], b = s[1];
    union { s16x8 v; unsigned short u[8]; } p;
    p.u[0] = f2bf(a.x); p.u[1] = f2bf(a.y); p.u[2] = f2bf(a.z); p.u[3] = f2bf(a.w);
    p.u[4] = f2bf(b.x); p.u[5] = f2bf(b.y); p.u[6] = f2bf(b.z); p.u[7] = f2bf(b.w);
    reinterpret_cast<s16x8*>(dst)[i] = p.v;
}

// ---------------- mean aggregation (bf16 in/out): one wave per node ----------------
__global__ void __launch_bounds__(256) agg_kernel(const unsigned short* __restrict__ x,
                                                  const int* __restrict__ row,
                                                  const int* __restrict__ cnt,
                                                  const int* __restrict__ es,
                                                  unsigned short* __restrict__ mean,
                                                  int nodebase) {
    int wave = (blockIdx.x * 256 + threadIdx.x) >> 6;
    int lane = threadIdx.x & 63;
    if (wave >= N_NODES) return;
    int gi = nodebase + wave;
    int start = row[gi];
    int deg = cnt[gi];
    float ax = 0.f, ay = 0.f;
    for (int c = 0; c < deg; c += 64) {
        int m = min(64, deg - c);
        int eid = (lane < m) ? es[start + c + lane] : 0;
        int j = 0;
        for (; j + 4 <= m; j += 4) {
            int s0 = __shfl(eid, j,     64);
            int s1 = __shfl(eid, j + 1, 64);
            int s2 = __shfl(eid, j + 2, 64);
            int s3 = __shfl(eid, j + 3, 64);
            unsigned int v0 = *reinterpret_cast<const unsigned int*>(x + (size_t)s0 * 128 + lane * 2);
            unsigned int v1 = *reinterpret_cast<const unsigned int*>(x + (size_t)s1 * 128 + lane * 2);
            unsigned int v2 = *reinterpret_cast<const unsigned int*>(x + (size_t)s2 * 128 + lane * 2);
            unsigned int v3 = *reinterpret_cast<const unsigned int*>(x + (size_t)s3 * 128 + lane * 2);
            ax += bflo(v0) + bflo(v1) + bflo(v2) + bflo(v3);
            ay += bfhi(v0) + bfhi(v1) + bfhi(v2) + bfhi(v3);
        }
        for (; j < m; ++j) {
            int s = __shfl(eid, j, 64);
            unsigned int v = *reinterpret_cast<const unsigned int*>(x + (size_t)s * 128 + lane * 2);
            ax += bflo(v); ay += bfhi(v);
        }
    }
    float inv = 1.0f / fmaxf((float)deg, 1.0f);
    unsigned int r = (unsigned int)f2bf(ax * inv) | ((unsigned int)f2bf(ay * inv) << 16);
    *reinterpret_cast<unsigned int*>(mean + (size_t)wave * 128 + lane * 2) = r;
}

// ---------------- MFMA GEMM: relu([mean|x] @ [Wl;Wr]^T + b), K=256 fused ----------------
__global__ void __launch_bounds__(256) gemm_mfma(const unsigned short* __restrict__ Am,
                                                 const unsigned short* __restrict__ Ax,
                                                 const unsigned short* __restrict__ Bl,
                                                 const unsigned short* __restrict__ Br,
                                                 const float* __restrict__ bias,
                                                 unsigned short* __restrict__ outH,
                                                 float* __restrict__ pool,
                                                 const int* __restrict__ batch,
                                                 int poolBase) {
    __shared__ s16x8 lds_a[2][256];   // [64 rows][4 slots of 8 bf16]
    __shared__ s16x8 lds_b[2][512];   // [128 rows][4 slots]

    const int tid = threadIdx.x;
    const int lane = tid & 63;
    const int w = tid >> 6;
    const int node0 = blockIdx.x * 64;

    const int wr = w >> 1;
    const int wc = w & 1;
    const int fr = lane & 15;
    const int fg = lane >> 4;

    f32x4 acc[2][4];
    #pragma unroll
    for (int mf = 0; mf < 2; ++mf)
        #pragma unroll
        for (int nf = 0; nf < 4; ++nf) acc[mf][nf] = (f32x4){0.f, 0.f, 0.f, 0.f};

    const int sa_row = tid >> 2, sa_slot = tid & 3;
    const int sa_g = sa_slot ^ ((sa_row >> 1) & 3);
    const size_t a_off = (size_t)min(node0 + sa_row, N_NODES - 1) * 128 + sa_g * 8;
    const int sb_row0 = tid >> 2;
    const size_t b_off0 = (size_t)sb_row0 * 128 + (sa_slot ^ ((sb_row0 >> 1) & 3)) * 8;
    const int sb_row1 = 64 + (tid >> 2);
    const size_t b_off1 = (size_t)sb_row1 * 128 + (sa_slot ^ ((sb_row1 >> 1) & 3)) * 8;

    const int arow0 = wr * 32 + fr;
    const int arow1 = arow0 + 16;
    const int aidx0 = arow0 * 4 + (fg ^ ((arow0 >> 1) & 3));
    const int aidx1 = arow1 * 4 + (fg ^ ((arow1 >> 1) & 3));
    int bidx[4];
    #pragma unroll
    for (int nf = 0; nf < 4; ++nf) {
        int br = wc * 64 + nf * 16 + fr;
        bidx[nf] = br * 4 + (fg ^ ((br >> 1) & 3));
    }

    #define LOAD_A(kc) (*reinterpret_cast<const s16x8*>(((kc) < 4 ? Am : Ax) + (((kc) & 3) * 32) + a_off))
    #define LOAD_B0(kc) (*reinterpret_cast<const s16x8*>(((kc) < 4 ? Bl : Br) + (((kc) & 3) * 32) + b_off0))
    #define LOAD_B1(kc) (*reinterpret_cast<const s16x8*>(((kc) < 4 ? Bl : Br) + (((kc) & 3) * 32) + b_off1))

    {
        s16x8 ra = LOAD_A(0), rb0 = LOAD_B0(0), rb1 = LOAD_B1(0);
        lds_a[0][tid] = ra; lds_b[0][tid] = rb0; lds_b[0][256 + tid] = rb1;
    }
    __syncthreads();

    #pragma unroll
    for (int kc = 0; kc < 8; ++kc) {
        const int cur = kc & 1;
        s16x8 ra, rb0, rb1;
        if (kc < 7) { ra = LOAD_A(kc + 1); rb0 = LOAD_B0(kc + 1); rb1 = LOAD_B1(kc + 1); }
        s16x8 a0 = lds_a[cur][aidx0];
        s16x8 a1 = lds_a[cur][aidx1];
        #pragma unroll
        for (int nf = 0; nf < 4; ++nf) {
            s16x8 bv = lds_b[cur][bidx[nf]];
            acc[0][nf] = __builtin_amdgcn_mfma_f32_16x16x32_bf16(a0, bv, acc[0][nf], 0, 0, 0);
            acc[1][nf] = __builtin_amdgcn_mfma_f32_16x16x32_bf16(a1, bv, acc[1][nf], 0, 0, 0);
        }
        if (kc < 7) { lds_a[cur ^ 1][tid] = ra; lds_b[cur ^ 1][tid] = rb0; lds_b[cur ^ 1][256 + tid] = rb1; }
        __syncthreads();
    }
    #undef LOAD_A
    #undef LOAD_B0
    #undef LOAD_B1

    if (outH) {
        #pragma unroll
        for (int mf = 0; mf < 2; ++mf)
            #pragma unroll
            for (int nf = 0; nf < 4; ++nf) {
                int col = wc * 64 + nf * 16 + fr;
                float bv = bias[col];
                #pragma unroll
                for (int r = 0; r < 4; ++r) {
                    int node = node0 + wr * 32 + mf * 16 + fg * 4 + r;
                    if (node < N_NODES)
                        outH[(size_t)node * 128 + col] = f2bf(fmaxf(acc[mf][nf][r] + bv, 0.f));
                }
            }
    } else {
        int gids[2][4];
        #pragma unroll
        for (int mf = 0; mf < 2; ++mf)
            #pragma unroll
            for (int r = 0; r < 4; ++r) {
                int node = node0 + wr * 32 + mf * 16 + fg * 4 + r;
                gids[mf][r] = (node < N_NODES) ? batch[node] : -1;
            }
        #pragma unroll
        for (int nf = 0; nf < 4; ++nf) {
            int col = wc * 64 + nf * 16 + fr;
            float bv = bias[col];
            float* pbase = &pool[poolBase + col];
            int curg = -1; float s = 0.f;
            #pragma unroll
            for (int mf = 0; mf < 2; ++mf)
                #pragma unroll
                for (int r = 0; r < 4; ++r) {
                    int g = gids[mf][r];
                    if (g < 0) continue;
                    float v = fmaxf(acc[mf][nf][r] + bv, 0.f);
                    if (g != curg) {
                        if (curg >= 0) atomicAdd(pbase + (size_t)curg * 256, s);
                        curg = g; s = v;
                    } else s += v;
                }
            if (curg >= 0) atomicAdd(pbase + (size_t)curg * 256, s);
        }
    }
}

// ---------------- MLP head + log_softmax, one block per graph ----------------
__global__ void __launch_bounds__(128) head_kernel(const float* __restrict__ pool,
                                                   const float* __restrict__ W1, const float* __restrict__ bh1,
                                                   const float* __restrict__ W2, const float* __restrict__ bh2,
                                                   const float* __restrict__ W3, const float* __restrict__ bh3,
                                                   float* __restrict__ out) {
    __shared__ float xg[256];
    __shared__ float h1[128];
    __shared__ float h2[64];
    __shared__ float lg[2];
    int g = blockIdx.x, t = threadIdx.x;
    xg[t] = pool[(size_t)g * 256 + t];
    xg[t + 128] = pool[(size_t)g * 256 + 128 + t];
    __syncthreads();
    float s = bh1[t];
    for (int k = 0; k < 256; ++k) s += W1[t * 256 + k] * xg[k];
    h1[t] = fmaxf(s, 0.f);
    __syncthreads();
    if (t < 64) {
        float s2 = bh2[t];
        for (int k = 0; k < 128; ++k) s2 += W2[t * 128 + k] * h1[k];
        h2[t] = fmaxf(s2, 0.f);
    }
    __syncthreads();
    if (t < 2) {
        float s3 = bh3[t];
        for (int k = 0; k < 64; ++k) s3 += W3[t * 64 + k] * h2[k];
        lg[t] = s3;
    }
    __syncthreads();
    if (t == 0) {
        float m = fmaxf(lg[0], lg[1]);
        float lse = m + logf(expf(lg[0] - m) + expf(lg[1] - m));
        out[g * 2 + 0] = lg[0] - lse;
        out[g * 2 + 1] = lg[1] - lse;
    }
}

extern "C" void kernel_launch(void* const* d_in, const int* in_sizes, int n_in,
                              void* d_out, int out_size, void* d_ws, size_t ws_size,
                              hipStream_t stream) {
    const float* sc_x = (const float*)d_in[0];
    const float* fc_x = (const float*)d_in[1];
    const int* sc_e   = (const int*)d_in[2];
    const int* fc_e   = (const int*)d_in[3];
    const int* batch  = (const int*)d_in[4];
    const float* sc_Wl1 = (const float*)d_in[5];
    const float* sc_Wr1 = (const float*)d_in[6];
    const float* sc_b1  = (const float*)d_in[7];
    const float* sc_Wl2 = (const float*)d_in[8];
    const float* sc_Wr2 = (const float*)d_in[9];
    const float* sc_b2  = (const float*)d_in[10];
    const float* fc_Wl1 = (const float*)d_in[11];
    const float* fc_Wr1 = (const float*)d_in[12];
    const float* fc_b1  = (const float*)d_in[13];
    const float* fc_Wl2 = (const float*)d_in[14];
    const float* fc_Wr2 = (const float*)d_in[15];
    const float* fc_b2  = (const float*)d_in[16];
    const float* W1  = (const float*)d_in[17];
    const float* bh1 = (const float*)d_in[18];
    const float* W2  = (const float*)d_in[19];
    const float* bh2 = (const float*)d_in[20];
    const float* W3  = (const float*)d_in[21];
    const float* bh3 = (const float*)d_in[22];

    int* iw = (int*)d_ws;
    float* fw = (float*)d_ws;
    float* pool = fw + O_POOL;
    int* gcur   = iw + O_GCUR;
    int* bstart = iw + O_BSTART;
    int* row    = iw + O_ROW;
    int* cnt    = iw + O_CNT;
    int* es     = iw + O_ES;
    unsigned short* WB    = (unsigned short*)(iw + O_WB);
    unsigned short* xb    = (unsigned short*)(iw + O_XB);
    unsigned short* meanb = (unsigned short*)(iw + O_MEAN);
    unsigned short* hb    = (unsigned short*)(iw + O_HB);
    unsigned int* buf = (unsigned int*)(iw + O_MEAN);   // aliased: build-time only

    hipMemsetAsync(d_ws, 0, ZERO_BYTES, stream);

    // CSR build via 2-pass binned counting sort (all global writes coalesced)
    bin_pass1<<<(2 * E_EDGES + 4095) / 4096, 512, 0, stream>>>(sc_e, fc_e, gcur, buf);
    bstart_scan<<<1, 512, 0, stream>>>(gcur, bstart);
    bin_pass2<<<NBUCK, 256, 0, stream>>>(buf, gcur, bstart, row, cnt, es);

    cvt_w_kernel<<<dim3(64, 8), 256, 0, stream>>>(sc_Wl1, sc_Wr1, sc_Wl2, sc_Wr2,
                                                  fc_Wl1, fc_Wr1, fc_Wl2, fc_Wr2, WB);

    const int AGB = (N_NODES + 3) / 4;
    const int CVB = ((N_NODES * 128) / 8 + 255) / 256;
    const int GGB = (N_NODES + 63) / 64;

    // SC branch
    cvt_x_kernel<<<CVB, 256, 0, stream>>>(sc_x, xb);
    agg_kernel<<<AGB, 256, 0, stream>>>(xb, row, cnt, es, meanb, 0);
    gemm_mfma<<<GGB, 256, 0, stream>>>(meanb, xb, WB + 0 * 16384, WB + 1 * 16384, sc_b1,
                                       hb, nullptr, nullptr, 0);
    agg_kernel<<<AGB, 256, 0, stream>>>(hb, row, cnt, es, meanb, 0);
    gemm_mfma<<<GGB, 256, 0, stream>>>(meanb, hb, WB + 2 * 16384, WB + 3 * 16384, sc_b2,
                                       nullptr, pool, batch, 0);
    // FC branch
    cvt_x_kernel<<<CVB, 256, 0, stream>>>(fc_x, xb);
    agg_kernel<<<AGB, 256, 0, stream>>>(xb, row, cnt, es, meanb, N_NODES);
    gemm_mfma<<<GGB, 256, 0, stream>>>(meanb, xb, WB + 4 * 16384, WB + 5 * 16384, fc_b1,
                                       hb, nullptr, nullptr, 0);
    agg_kernel<<<AGB, 256, 0, stream>>>(hb, row, cnt, es, meanb, N_NODES);
    gemm_mfma<<<GGB, 256, 0, stream>>>(meanb, hb, WB + 6 * 16384, WB + 7 * 16384, fc_b2,
                                       nullptr, pool, batch, 128);

    head_kernel<<<G_GRAPHS, 128, 0, stream>>>(pool, W1, bh1, W2, bh2, W3, bh3, (float*)d_out);
}

// Round 7
// 351.538 us; speedup vs baseline: 2.6132x; 1.1118x over previous
//
#include <hip/hip_runtime.h>
#include <hip/hip_bf16.h>

#define N_NODES 50000
#define E_EDGES 800000
#define G_GRAPHS 64
#define NBUCK 392            // 2 sets * 196 buckets of 256 nodes
#define BCAP 5120            // per-bucket capacity (mean 4096, sigma 64)
#define NF ((size_t)N_NODES * 128)

typedef __attribute__((ext_vector_type(8))) short s16x8;   // 8 bf16 (4 VGPRs)
typedef __attribute__((ext_vector_type(4))) float f32x4;   // MFMA acc

// ---------------- workspace layout (4-byte words) ----------------
// (Round 6 bug: O_XB overlapped WB — WB is 8*16384 bf16 = 65536 WORDS. Fixed.)
constexpr size_t O_POOL   = 0;        // float[16384]  [G][256] pooled (sc|fc)
constexpr size_t O_GCUR   = 16384;    // int[512]      bucket fill cursors
constexpr size_t O_BSTART = 16896;    // int[512]      bucket start offsets
constexpr size_t O_ROW    = 17408;    // int[100000]   CSR row starts
constexpr size_t O_CNT    = 117408;   // int[100000]   per-node in-degree
constexpr size_t O_ES     = 217408;   // int[1600000]  src ids sorted by dst
constexpr size_t O_WB     = 1817408;  // bf16[8*16384] = 65536 words, ends 1882944
constexpr size_t O_XB     = 1882944;  // bf16[2*50000*128] = 6.4M words, ends 8282944
constexpr size_t O_MEAN   = 8282944;  // bf16[2*50000*128]; aliased as bucket buf (8.03MB < 12.8MB)
constexpr size_t O_HB     = 14682944; // bf16[2*50000*128], ends 21082944 (~84MB)
constexpr size_t ZERO_BYTES = (16384 + 512) * 4;   // pool + gcur

__device__ __forceinline__ unsigned short f2bf(float f) {
    __hip_bfloat16 h = __float2bfloat16(f);
    return *reinterpret_cast<unsigned short*>(&h);
}
__device__ __forceinline__ float bflo(unsigned int v) { return __uint_as_float(v << 16); }
__device__ __forceinline__ float bfhi(unsigned int v) { return __uint_as_float(v & 0xffff0000u); }

// ---------------- pass 1: bin edges into 392 dst-range buckets ----------------
__global__ void __launch_bounds__(512) bin_pass1(const int* __restrict__ sc_e,
                                                 const int* __restrict__ fc_e,
                                                 int* __restrict__ gcur,
                                                 unsigned int* __restrict__ buf) {
    __shared__ int hcnt[512];
    __shared__ int hexcl[512];
    __shared__ int hcur[512];
    __shared__ int gbase[512];
    __shared__ int wsum[8];
    __shared__ unsigned int stage[4096];

    const int tid = threadIdx.x;
    const int lane = tid & 63;
    const int wid = tid >> 6;
    const int tile0 = blockIdx.x * 4096;

    hcnt[tid] = 0;
    __syncthreads();

    int eb[8];
    unsigned int pk[8];
    #pragma unroll
    for (int j = 0; j < 8; ++j) {
        int ec = tile0 + j * 512 + tid;
        if (ec < 2 * E_EDGES) {
            int set = (ec >= E_EDGES);
            int local = ec - set * E_EDGES;
            const int* ep = set ? fc_e : sc_e;
            int src = ep[local];
            int dst = ep[E_EDGES + local];
            eb[j] = set * 196 + (dst >> 8);
            pk[j] = ((unsigned int)(dst & 255) << 16) | (unsigned int)src;
            atomicAdd(&hcnt[eb[j]], 1);
        } else eb[j] = -1;
    }
    __syncthreads();

    {
        int v = hcnt[tid];
        int incl = v;
        #pragma unroll
        for (int d = 1; d < 64; d <<= 1) {
            int u = __shfl_up(incl, d, 64);
            if (lane >= d) incl += u;
        }
        if (lane == 63) wsum[wid] = incl;
        __syncthreads();
        int pre = 0;
        for (int w = 0; w < wid; ++w) pre += wsum[w];
        int excl = incl - v + pre;
        hexcl[tid] = excl;
        hcur[tid] = excl;
    }
    __syncthreads();

    if (tid < NBUCK) {
        int c = hcnt[tid];
        gbase[tid] = c ? atomicAdd(&gcur[tid], c) : 0;
    }

    #pragma unroll
    for (int j = 0; j < 8; ++j) {
        if (eb[j] >= 0) {
            int pos = atomicAdd(&hcur[eb[j]], 1);
            stage[pos] = pk[j];
        }
    }
    __syncthreads();

    for (int b = wid; b < NBUCK; b += 8) {
        int c = hcnt[b];
        if (!c) continue;
        int s = hexcl[b];
        int g0 = gbase[b];
        for (int i = lane; i < c; i += 64) {
            int gi = g0 + i;
            if (gi < BCAP) buf[(size_t)b * BCAP + gi] = stage[s + i];
        }
    }
}

// ---------------- tiny exclusive scan over bucket sizes ----------------
__global__ void bstart_scan(const int* __restrict__ gcur, int* __restrict__ bstart) {
    __shared__ int wsum[8];
    int t = threadIdx.x;
    int lane = t & 63, wid = t >> 6;
    int v = (t < NBUCK) ? min(gcur[t], BCAP) : 0;
    int incl = v;
    #pragma unroll
    for (int d = 1; d < 64; d <<= 1) {
        int u = __shfl_up(incl, d, 64);
        if (lane >= d) incl += u;
    }
    if (lane == 63) wsum[wid] = incl;
    __syncthreads();
    int pre = 0;
    for (int w = 0; w < wid; ++w) pre += wsum[w];
    if (t < NBUCK) bstart[t] = incl - v + pre;
}

// ---------------- pass 2: per-bucket counting sort -> es, cnt, row ----------------
__global__ void __launch_bounds__(256) bin_pass2(const unsigned int* __restrict__ buf,
                                                 const int* __restrict__ gcur,
                                                 const int* __restrict__ bstart,
                                                 int* __restrict__ row,
                                                 int* __restrict__ cnt,
                                                 int* __restrict__ es) {
    __shared__ int cntl[256];
    __shared__ int pexcl[256];
    __shared__ int pcur[256];
    __shared__ int wsum[4];
    __shared__ int stage[BCAP];

    const int b = blockIdx.x;
    const int tid = threadIdx.x;
    const int lane = tid & 63, wid = tid >> 6;
    const int sz = min(gcur[b], BCAP);
    const unsigned int* mybuf = buf + (size_t)b * BCAP;
    const int n0 = (b % 196) * 256;
    const int setbase = (b / 196) * N_NODES;

    cntl[tid] = 0;
    __syncthreads();
    for (int i = tid; i < sz; i += 256)
        atomicAdd(&cntl[mybuf[i] >> 16], 1);
    __syncthreads();
    {
        int v = cntl[tid];
        int incl = v;
        #pragma unroll
        for (int d = 1; d < 64; d <<= 1) {
            int u = __shfl_up(incl, d, 64);
            if (lane >= d) incl += u;
        }
        if (lane == 63) wsum[wid] = incl;
        __syncthreads();
        int pre = 0;
        for (int w = 0; w < wid; ++w) pre += wsum[w];
        int excl = incl - v + pre;
        pexcl[tid] = excl;
        pcur[tid] = excl;
    }
    __syncthreads();
    for (int i = tid; i < sz; i += 256) {
        unsigned int p = mybuf[i];
        int pos = atomicAdd(&pcur[p >> 16], 1);
        stage[pos] = (int)(p & 0xFFFFu);
    }
    __syncthreads();
    const int base = bstart[b];
    for (int i = tid; i < sz; i += 256) es[base + i] = stage[i];
    int node = n0 + tid;
    if (node < N_NODES) {
        cnt[setbase + node] = cntl[tid];
        row[setbase + node] = base + pexcl[tid];
    }
}

// ---------------- weight convert fp32 -> bf16, layout kept [o][k] ----------------
__global__ void cvt_w_kernel(const float* w0, const float* w1, const float* w2, const float* w3,
                             const float* w4, const float* w5, const float* w6, const float* w7,
                             unsigned short* __restrict__ wb) {
    const float* W;
    int m = blockIdx.y;
    switch (m) {
        case 0: W = w0; break; case 1: W = w1; break;
        case 2: W = w2; break; case 3: W = w3; break;
        case 4: W = w4; break; case 5: W = w5; break;
        case 6: W = w6; break; default: W = w7; break;
    }
    int i = blockIdx.x * 256 + threadIdx.x;
    wb[(size_t)m * 16384 + i] = f2bf(W[i]);
}

// ---------------- feature convert fp32 -> bf16, both sets ----------------
__global__ void cvt_x_kernel(const float* __restrict__ sc_x, const float* __restrict__ fc_x,
                             unsigned short* __restrict__ dst) {
    int i = blockIdx.x * 256 + threadIdx.x;   // over 2*800000 groups of 8
    if (i >= 2 * (N_NODES * 128) / 8) return;
    int set = (i >= (N_NODES * 128) / 8);
    int local = i - set * (N_NODES * 128) / 8;
    const float* src = set ? fc_x : sc_x;
    const float4* s = reinterpret_cast<const float4*>(src) + (size_t)local * 2;
    float4 a = s[0], b = s[1];
    union { s16x8 v; unsigned short u[8]; } p;
    p.u[0] = f2bf(a.x); p.u[1] = f2bf(a.y); p.u[2] = f2bf(a.z); p.u[3] = f2bf(a.w);
    p.u[4] = f2bf(b.x); p.u[5] = f2bf(b.y); p.u[6] = f2bf(b.z); p.u[7] = f2bf(b.w);
    reinterpret_cast<s16x8*>(dst)[i] = p.v;
}

// ---------------- mean aggregation: quarter-wave (16 lanes/node, 16B loads) ----------------
__global__ void __launch_bounds__(256) agg_kernel(const unsigned short* __restrict__ x,
                                                  const int* __restrict__ row,
                                                  const int* __restrict__ cnt,
                                                  const int* __restrict__ es,
                                                  unsigned short* __restrict__ mean) {
    int wave = (blockIdx.x * 256 + threadIdx.x) >> 6;
    int lane = threadIdx.x & 63;
    int ql = lane & 15;
    int n = wave * 4 + (lane >> 4);          // node in [0, 2*N_NODES)
    if (n >= 2 * N_NODES) return;
    const unsigned short* xs = x + (n >= N_NODES ? NF : 0);
    int start = row[n];
    int deg = cnt[n];
    float a0 = 0.f, a1 = 0.f, a2 = 0.f, a3 = 0.f, a4 = 0.f, a5 = 0.f, a6 = 0.f, a7 = 0.f;
    int qbase = lane & 48;
    for (int c = 0; c < deg; c += 16) {
        int m = min(16, deg - c);
        int eid = (ql < m) ? es[start + c + ql] : 0;
        int j = 0;
        for (; j + 4 <= m; j += 4) {
            int s0 = __shfl(eid, qbase + j,     64);
            int s1 = __shfl(eid, qbase + j + 1, 64);
            int s2 = __shfl(eid, qbase + j + 2, 64);
            int s3 = __shfl(eid, qbase + j + 3, 64);
            uint4 v0 = *reinterpret_cast<const uint4*>(xs + (size_t)s0 * 128 + ql * 8);
            uint4 v1 = *reinterpret_cast<const uint4*>(xs + (size_t)s1 * 128 + ql * 8);
            uint4 v2 = *reinterpret_cast<const uint4*>(xs + (size_t)s2 * 128 + ql * 8);
            uint4 v3 = *reinterpret_cast<const uint4*>(xs + (size_t)s3 * 128 + ql * 8);
            a0 += bflo(v0.x) + bflo(v1.x) + bflo(v2.x) + bflo(v3.x);
            a1 += bfhi(v0.x) + bfhi(v1.x) + bfhi(v2.x) + bfhi(v3.x);
            a2 += bflo(v0.y) + bflo(v1.y) + bflo(v2.y) + bflo(v3.y);
            a3 += bfhi(v0.y) + bfhi(v1.y) + bfhi(v2.y) + bfhi(v3.y);
            a4 += bflo(v0.z) + bflo(v1.z) + bflo(v2.z) + bflo(v3.z);
            a5 += bfhi(v0.z) + bfhi(v1.z) + bfhi(v2.z) + bfhi(v3.z);
            a6 += bflo(v0.w) + bflo(v1.w) + bflo(v2.w) + bflo(v3.w);
            a7 += bfhi(v0.w) + bfhi(v1.w) + bfhi(v2.w) + bfhi(v3.w);
        }
        for (; j < m; ++j) {
            int s = __shfl(eid, qbase + j, 64);
            uint4 v = *reinterpret_cast<const uint4*>(xs + (size_t)s * 128 + ql * 8);
            a0 += bflo(v.x); a1 += bfhi(v.x);
            a2 += bflo(v.y); a3 += bfhi(v.y);
            a4 += bflo(v.z); a5 += bfhi(v.z);
            a6 += bflo(v.w); a7 += bfhi(v.w);
        }
    }
    float inv = 1.0f / fmaxf((float)deg, 1.0f);
    uint4 o;
    o.x = (unsigned int)f2bf(a0 * inv) | ((unsigned int)f2bf(a1 * inv) << 16);
    o.y = (unsigned int)f2bf(a2 * inv) | ((unsigned int)f2bf(a3 * inv) << 16);
    o.z = (unsigned int)f2bf(a4 * inv) | ((unsigned int)f2bf(a5 * inv) << 16);
    o.w = (unsigned int)f2bf(a6 * inv) | ((unsigned int)f2bf(a7 * inv) << 16);
    *reinterpret_cast<uint4*>(mean + (size_t)n * 128 + ql * 8) = o;
}

// ---------------- MFMA GEMM: relu([mean|x] @ [Wl;Wr]^T + b); blockIdx.y = set ----------------
__global__ void __launch_bounds__(256) gemm_mfma(const unsigned short* __restrict__ AmB,
                                                 const unsigned short* __restrict__ AxB,
                                                 const unsigned short* __restrict__ WBall,
                                                 const float* __restrict__ bias0,
                                                 const float* __restrict__ bias1,
                                                 unsigned short* __restrict__ outHB,
                                                 float* __restrict__ pool,
                                                 const int* __restrict__ batch,
                                                 int layer) {
    __shared__ s16x8 lds_a[2][256];   // [64 rows][4 slots of 8 bf16]
    __shared__ s16x8 lds_b[2][512];   // [128 rows][4 slots]

    const int tid = threadIdx.x;
    const int lane = tid & 63;
    const int w = tid >> 6;
    const int set = blockIdx.y;
    const int node0 = blockIdx.x * 64;

    const unsigned short* Am = AmB + (size_t)set * NF;
    const unsigned short* Ax = AxB + (size_t)set * NF;
    const unsigned short* Bl = WBall + (size_t)(set * 4 + layer * 2) * 16384;
    const unsigned short* Br = Bl + 16384;
    const float* bias = set ? bias1 : bias0;
    unsigned short* outH = outHB ? outHB + (size_t)set * NF : nullptr;
    const int poolBase = set * 128;

    const int wr = w >> 1;
    const int wc = w & 1;
    const int fr = lane & 15;
    const int fg = lane >> 4;

    f32x4 acc[2][4];
    #pragma unroll
    for (int mf = 0; mf < 2; ++mf)
        #pragma unroll
        for (int nf = 0; nf < 4; ++nf) acc[mf][nf] = (f32x4){0.f, 0.f, 0.f, 0.f};

    const int sa_row = tid >> 2, sa_slot = tid & 3;
    const int sa_g = sa_slot ^ ((sa_row >> 1) & 3);
    const size_t a_off = (size_t)min(node0 + sa_row, N_NODES - 1) * 128 + sa_g * 8;
    const int sb_row0 = tid >> 2;
    const size_t b_off0 = (size_t)sb_row0 * 128 + (sa_slot ^ ((sb_row0 >> 1) & 3)) * 8;
    const int sb_row1 = 64 + (tid >> 2);
    const size_t b_off1 = (size_t)sb_row1 * 128 + (sa_slot ^ ((sb_row1 >> 1) & 3)) * 8;

    const int arow0 = wr * 32 + fr;
    const int arow1 = arow0 + 16;
    const int aidx0 = arow0 * 4 + (fg ^ ((arow0 >> 1) & 3));
    const int aidx1 = arow1 * 4 + (fg ^ ((arow1 >> 1) & 3));
    int bidx[4];
    #pragma unroll
    for (int nf = 0; nf < 4; ++nf) {
        int br = wc * 64 + nf * 16 + fr;
        bidx[nf] = br * 4 + (fg ^ ((br >> 1) & 3));
    }

    #define LOAD_A(kc) (*reinterpret_cast<const s16x8*>(((kc) < 4 ? Am : Ax) + (((kc) & 3) * 32) + a_off))
    #define LOAD_B0(kc) (*reinterpret_cast<const s16x8*>(((kc) < 4 ? Bl : Br) + (((kc) & 3) * 32) + b_off0))
    #define LOAD_B1(kc) (*reinterpret_cast<const s16x8*>(((kc) < 4 ? Bl : Br) + (((kc) & 3) * 32) + b_off1))

    {
        s16x8 ra = LOAD_A(0), rb0 = LOAD_B0(0), rb1 = LOAD_B1(0);
        lds_a[0][tid] = ra; lds_b[0][tid] = rb0; lds_b[0][256 + tid] = rb1;
    }
    __syncthreads();

    #pragma unroll
    for (int kc = 0; kc < 8; ++kc) {
        const int cur = kc & 1;
        s16x8 ra, rb0, rb1;
        if (kc < 7) { ra = LOAD_A(kc + 1); rb0 = LOAD_B0(kc + 1); rb1 = LOAD_B1(kc + 1); }
        s16x8 a0 = lds_a[cur][aidx0];
        s16x8 a1 = lds_a[cur][aidx1];
        #pragma unroll
        for (int nf = 0; nf < 4; ++nf) {
            s16x8 bv = lds_b[cur][bidx[nf]];
            acc[0][nf] = __builtin_amdgcn_mfma_f32_16x16x32_bf16(a0, bv, acc[0][nf], 0, 0, 0);
            acc[1][nf] = __builtin_amdgcn_mfma_f32_16x16x32_bf16(a1, bv, acc[1][nf], 0, 0, 0);
        }
        if (kc < 7) { lds_a[cur ^ 1][tid] = ra; lds_b[cur ^ 1][tid] = rb0; lds_b[cur ^ 1][256 + tid] = rb1; }
        __syncthreads();
    }
    #undef LOAD_A
    #undef LOAD_B0
    #undef LOAD_B1

    if (outH) {
        #pragma unroll
        for (int mf = 0; mf < 2; ++mf)
            #pragma unroll
            for (int nf = 0; nf < 4; ++nf) {
                int col = wc * 64 + nf * 16 + fr;
                float bv = bias[col];
                #pragma unroll
                for (int r = 0; r < 4; ++r) {
                    int node = node0 + wr * 32 + mf * 16 + fg * 4 + r;
                    if (node < N_NODES)
                        outH[(size_t)node * 128 + col] = f2bf(fmaxf(acc[mf][nf][r] + bv, 0.f));
                }
            }
    } else {
        int gids[2][4];
        #pragma unroll
        for (int mf = 0; mf < 2; ++mf)
            #pragma unroll
            for (int r = 0; r < 4; ++r) {
                int node = node0 + wr * 32 + mf * 16 + fg * 4 + r;
                gids[mf][r] = (node < N_NODES) ? batch[node] : -1;
            }
        #pragma unroll
        for (int nf = 0; nf < 4; ++nf) {
            int col = wc * 64 + nf * 16 + fr;
            float bv = bias[col];
            float* pbase = &pool[poolBase + col];
            int curg = -1; float s = 0.f;
            #pragma unroll
            for (int mf = 0; mf < 2; ++mf)
                #pragma unroll
                for (int r = 0; r < 4; ++r) {
                    int g = gids[mf][r];
                    if (g < 0) continue;
                    float v = fmaxf(acc[mf][nf][r] + bv, 0.f);
                    if (g != curg) {
                        if (curg >= 0) atomicAdd(pbase + (size_t)curg * 256, s);
                        curg = g; s = v;
                    } else s += v;
                }
            if (curg >= 0) atomicAdd(pbase + (size_t)curg * 256, s);
        }
    }
}

// ---------------- MLP head + log_softmax, one block per graph ----------------
__global__ void __launch_bounds__(128) head_kernel(const float* __restrict__ pool,
                                                   const float* __restrict__ W1, const float* __restrict__ bh1,
                                                   const float* __restrict__ W2, const float* __restrict__ bh2,
                                                   const float* __restrict__ W3, const float* __restrict__ bh3,
                                                   float* __restrict__ out) {
    __shared__ float xg[256];
    __shared__ float h1[128];
    __shared__ float h2[64];
    __shared__ float lg[2];
    int g = blockIdx.x, t = threadIdx.x;
    xg[t] = pool[(size_t)g * 256 + t];
    xg[t + 128] = pool[(size_t)g * 256 + 128 + t];
    __syncthreads();
    float s = bh1[t];
    for (int k = 0; k < 256; ++k) s += W1[t * 256 + k] * xg[k];
    h1[t] = fmaxf(s, 0.f);
    __syncthreads();
    if (t < 64) {
        float s2 = bh2[t];
        for (int k = 0; k < 128; ++k) s2 += W2[t * 128 + k] * h1[k];
        h2[t] = fmaxf(s2, 0.f);
    }
    __syncthreads();
    if (t < 2) {
        float s3 = bh3[t];
        for (int k = 0; k < 64; ++k) s3 += W3[t * 64 + k] * h2[k];
        lg[t] = s3;
    }
    __syncthreads();
    if (t == 0) {
        float m = fmaxf(lg[0], lg[1]);
        float lse = m + logf(expf(lg[0] - m) + expf(lg[1] - m));
        out[g * 2 + 0] = lg[0] - lse;
        out[g * 2 + 1] = lg[1] - lse;
    }
}

extern "C" void kernel_launch(void* const* d_in, const int* in_sizes, int n_in,
                              void* d_out, int out_size, void* d_ws, size_t ws_size,
                              hipStream_t stream) {
    const float* sc_x = (const float*)d_in[0];
    const float* fc_x = (const float*)d_in[1];
    const int* sc_e   = (const int*)d_in[2];
    const int* fc_e   = (const int*)d_in[3];
    const int* batch  = (const int*)d_in[4];
    const float* sc_Wl1 = (const float*)d_in[5];
    const float* sc_Wr1 = (const float*)d_in[6];
    const float* sc_b1  = (const float*)d_in[7];
    const float* sc_Wl2 = (const float*)d_in[8];
    const float* sc_Wr2 = (const float*)d_in[9];
    const float* sc_b2  = (const float*)d_in[10];
    const float* fc_Wl1 = (const float*)d_in[11];
    const float* fc_Wr1 = (const float*)d_in[12];
    const float* fc_b1  = (const float*)d_in[13];
    const float* fc_Wl2 = (const float*)d_in[14];
    const float* fc_Wr2 = (const float*)d_in[15];
    const float* fc_b2  = (const float*)d_in[16];
    const float* W1  = (const float*)d_in[17];
    const float* bh1 = (const float*)d_in[18];
    const float* W2  = (const float*)d_in[19];
    const float* bh2 = (const float*)d_in[20];
    const float* W3  = (const float*)d_in[21];
    const float* bh3 = (const float*)d_in[22];

    int* iw = (int*)d_ws;
    float* fw = (float*)d_ws;
    float* pool = fw + O_POOL;
    int* gcur   = iw + O_GCUR;
    int* bstart = iw + O_BSTART;
    int* row    = iw + O_ROW;
    int* cnt    = iw + O_CNT;
    int* es     = iw + O_ES;
    unsigned short* WB    = (unsigned short*)(iw + O_WB);
    unsigned short* xb    = (unsigned short*)(iw + O_XB);
    unsigned short* meanb = (unsigned short*)(iw + O_MEAN);
    unsigned short* hb    = (unsigned short*)(iw + O_HB);
    unsigned int* buf = (unsigned int*)(iw + O_MEAN);   // aliased: build-time only

    hipMemsetAsync(d_ws, 0, ZERO_BYTES, stream);

    // CSR build via 2-pass binned counting sort
    bin_pass1<<<(2 * E_EDGES + 4095) / 4096, 512, 0, stream>>>(sc_e, fc_e, gcur, buf);
    bstart_scan<<<1, 512, 0, stream>>>(gcur, bstart);
    bin_pass2<<<NBUCK, 256, 0, stream>>>(buf, gcur, bstart, row, cnt, es);

    cvt_w_kernel<<<dim3(64, 8), 256, 0, stream>>>(sc_Wl1, sc_Wr1, sc_Wl2, sc_Wr2,
                                                  fc_Wl1, fc_Wr1, fc_Wl2, fc_Wr2, WB);
    cvt_x_kernel<<<2 * 3125, 256, 0, stream>>>(sc_x, fc_x, xb);

    const int AGB = (2 * N_NODES + 15) / 16;    // 6250 blocks, 16 nodes/block
    dim3 gg((N_NODES + 63) / 64, 2);            // (782, 2)

    // layer 1 (both branches)
    agg_kernel<<<AGB, 256, 0, stream>>>(xb, row, cnt, es, meanb);
    gemm_mfma<<<gg, 256, 0, stream>>>(meanb, xb, WB, sc_b1, fc_b1, hb, nullptr, nullptr, 0);
    // layer 2 (both branches) + fused pool
    agg_kernel<<<AGB, 256, 0, stream>>>(hb, row, cnt, es, meanb);
    gemm_mfma<<<gg, 256, 0, stream>>>(meanb, hb, WB, sc_b2, fc_b2, nullptr, pool, batch, 1);

    head_kernel<<<G_GRAPHS, 128, 0, stream>>>(pool, W1, bh1, W2, bh2, W3, bh3, (float*)d_out);
}

// Round 9
// 342.695 us; speedup vs baseline: 2.6807x; 1.0258x over previous
//
#include <hip/hip_runtime.h>
#include <hip/hip_bf16.h>

#define N_NODES 50000
#define E_EDGES 800000
#define G_GRAPHS 64
#define NBUCK 392            // 2 sets * 196 buckets of 256 nodes
#define BCAP 5120            // per-bucket capacity (mean 4096, sigma 64)
#define NF ((size_t)N_NODES * 128)

typedef __attribute__((ext_vector_type(8))) short s16x8;   // 8 bf16 (4 VGPRs)
typedef __attribute__((ext_vector_type(4))) float f32x4;   // MFMA acc

// ---------------- workspace layout (4-byte words) ----------------
constexpr size_t O_POOL   = 0;        // float[16384]  [G][256] pooled (sc|fc)
constexpr size_t O_GCUR   = 16384;    // int[512]      bucket fill cursors
constexpr size_t O_ROW    = 17408;    // int[100000]   CSR row starts
constexpr size_t O_CNT    = 117408;   // int[100000]   per-node in-degree
constexpr size_t O_ES     = 217408;   // int[1600000]  src ids sorted by dst
constexpr size_t O_WB     = 1817408;  // bf16[8*16384] = 65536 words, ends 1882944
constexpr size_t O_XB     = 1882944;  // bf16[2*50000*128] = 6.4M words, ends 8282944
constexpr size_t O_MEAN   = 8282944;  // bf16[2*50000*128]; aliased as bucket buf (8.03MB < 12.8MB)
constexpr size_t O_HB     = 14682944; // bf16[2*50000*128], ends 21082944 (~84MB)
constexpr size_t ZERO_BYTES = (16384 + 512) * 4;   // pool + gcur

__device__ __forceinline__ unsigned short f2bf(float f) {
    __hip_bfloat16 h = __float2bfloat16(f);
    return *reinterpret_cast<unsigned short*>(&h);
}
__device__ __forceinline__ float bflo(unsigned int v) { return __uint_as_float(v << 16); }
__device__ __forceinline__ float bfhi(unsigned int v) { return __uint_as_float(v & 0xffff0000u); }

// ---------------- pass 1: bin edges into 392 dst-range buckets ----------------
__global__ void __launch_bounds__(512) bin_pass1(const int* __restrict__ sc_e,
                                                 const int* __restrict__ fc_e,
                                                 int* __restrict__ gcur,
                                                 unsigned int* __restrict__ buf) {
    __shared__ int hcnt[512];
    __shared__ int hexcl[512];
    __shared__ int hcur[512];
    __shared__ int gbase[512];
    __shared__ int wsum[8];
    __shared__ unsigned int stage[4096];

    const int tid = threadIdx.x;
    const int lane = tid & 63;
    const int wid = tid >> 6;
    const int tile0 = blockIdx.x * 4096;

    hcnt[tid] = 0;
    __syncthreads();

    int eb[8];
    unsigned int pk[8];
    #pragma unroll
    for (int j = 0; j < 8; ++j) {
        int ec = tile0 + j * 512 + tid;
        if (ec < 2 * E_EDGES) {
            int set = (ec >= E_EDGES);
            int local = ec - set * E_EDGES;
            const int* ep = set ? fc_e : sc_e;
            int src = ep[local];
            int dst = ep[E_EDGES + local];
            eb[j] = set * 196 + (dst >> 8);
            pk[j] = ((unsigned int)(dst & 255) << 16) | (unsigned int)src;
            atomicAdd(&hcnt[eb[j]], 1);
        } else eb[j] = -1;
    }
    __syncthreads();

    {
        int v = hcnt[tid];
        int incl = v;
        #pragma unroll
        for (int d = 1; d < 64; d <<= 1) {
            int u = __shfl_up(incl, d, 64);
            if (lane >= d) incl += u;
        }
        if (lane == 63) wsum[wid] = incl;
        __syncthreads();
        int pre = 0;
        for (int w = 0; w < wid; ++w) pre += wsum[w];
        int excl = incl - v + pre;
        hexcl[tid] = excl;
        hcur[tid] = excl;
    }
    __syncthreads();

    if (tid < NBUCK) {
        int c = hcnt[tid];
        gbase[tid] = c ? atomicAdd(&gcur[tid], c) : 0;
    }

    #pragma unroll
    for (int j = 0; j < 8; ++j) {
        if (eb[j] >= 0) {
            int pos = atomicAdd(&hcur[eb[j]], 1);
            stage[pos] = pk[j];
        }
    }
    __syncthreads();

    for (int b = wid; b < NBUCK; b += 8) {
        int c = hcnt[b];
        if (!c) continue;
        int s = hexcl[b];
        int g0 = gbase[b];
        for (int i = lane; i < c; i += 64) {
            int gi = g0 + i;
            if (gi < BCAP) buf[(size_t)b * BCAP + gi] = stage[s + i];
        }
    }
}

// ---------------- pass 2: per-bucket counting sort -> es, cnt, row ----------------
// bstart computed in-block (wave 0 scans all 392 bucket sizes; no separate scan kernel)
__global__ void __launch_bounds__(256) bin_pass2(const unsigned int* __restrict__ buf,
                                                 const int* __restrict__ gcur,
                                                 int* __restrict__ row,
                                                 int* __restrict__ cnt,
                                                 int* __restrict__ es) {
    __shared__ int cntl[256];
    __shared__ int pexcl[256];
    __shared__ int pcur[256];
    __shared__ int wsum[4];
    __shared__ int pre[512];
    __shared__ int stage[BCAP];

    const int b = blockIdx.x;
    const int tid = threadIdx.x;
    const int lane = tid & 63, wid = tid >> 6;
    const int sz = min(gcur[b], BCAP);
    const unsigned int* mybuf = buf + (size_t)b * BCAP;
    const int n0 = (b % 196) * 256;
    const int setbase = (b / 196) * N_NODES;

    // stage sizes into LDS for the in-block bstart scan
    pre[tid] = (tid < NBUCK) ? min(gcur[tid], BCAP) : 0;
    if (tid + 256 < 512) pre[tid + 256] = (tid + 256 < NBUCK) ? min(gcur[tid + 256], BCAP) : 0;
    cntl[tid] = 0;
    __syncthreads();
    // wave 0: serial-chunk exclusive scan of pre[512] in place
    if (tid < 64) {
        int base = tid * 8;
        int loc[8];
        int s = 0;
        #pragma unroll
        for (int k = 0; k < 8; ++k) { loc[k] = s; s += pre[base + k]; }
        int incl = s;
        #pragma unroll
        for (int d = 1; d < 64; d <<= 1) {
            int u = __shfl_up(incl, d, 64);
            if (lane >= d) incl += u;
        }
        int excl = incl - s;
        #pragma unroll
        for (int k = 0; k < 8; ++k) pre[base + k] = excl + loc[k];
    }
    // histogram own bucket
    for (int i = tid; i < sz; i += 256)
        atomicAdd(&cntl[mybuf[i] >> 16], 1);
    __syncthreads();
    const int base = pre[b];
    {
        int v = cntl[tid];
        int incl = v;
        #pragma unroll
        for (int d = 1; d < 64; d <<= 1) {
            int u = __shfl_up(incl, d, 64);
            if (lane >= d) incl += u;
        }
        if (lane == 63) wsum[wid] = incl;
        __syncthreads();
        int p = 0;
        for (int w = 0; w < wid; ++w) p += wsum[w];
        int excl = incl - v + p;
        pexcl[tid] = excl;
        pcur[tid] = excl;
    }
    __syncthreads();
    for (int i = tid; i < sz; i += 256) {
        unsigned int p = mybuf[i];
        int pos = atomicAdd(&pcur[p >> 16], 1);
        stage[pos] = (int)(p & 0xFFFFu);
    }
    __syncthreads();
    for (int i = tid; i < sz; i += 256) es[base + i] = stage[i];
    int node = n0 + tid;
    if (node < N_NODES) {
        cnt[setbase + node] = cntl[tid];
        row[setbase + node] = base + pexcl[tid];
    }
}

// ---------------- combined convert: x features (blocks <6250) + weights (last 64) ----------------
__global__ void cvt_all(const float* __restrict__ sc_x, const float* __restrict__ fc_x,
                        const float* w0, const float* w1, const float* w2, const float* w3,
                        const float* w4, const float* w5, const float* w6, const float* w7,
                        unsigned short* __restrict__ xb, unsigned short* __restrict__ wb) {
    const int blk = blockIdx.x;
    const int tid = threadIdx.x;
    if (blk < 6250) {
        int i = blk * 256 + tid;   // over 2*800000 groups of 8
        int set = (i >= (N_NODES * 128) / 8);
        int local = i - set * (N_NODES * 128) / 8;
        const float* src = set ? fc_x : sc_x;
        const float4* s = reinterpret_cast<const float4*>(src) + (size_t)local * 2;
        float4 a = s[0], b = s[1];
        union { s16x8 v; unsigned short u[8]; } p;
        p.u[0] = f2bf(a.x); p.u[1] = f2bf(a.y); p.u[2] = f2bf(a.z); p.u[3] = f2bf(a.w);
        p.u[4] = f2bf(b.x); p.u[5] = f2bf(b.y); p.u[6] = f2bf(b.z); p.u[7] = f2bf(b.w);
        reinterpret_cast<s16x8*>(xb)[i] = p.v;
    } else {
        int widx = blk - 6250;                 // [0,64)
        int gi = widx * 2048 + tid * 8;        // global bf16 index into WB
        int m = gi >> 14;                      // uniform per block
        int off = gi & 16383;
        const float* W;
        switch (m) {
            case 0: W = w0; break; case 1: W = w1; break;
            case 2: W = w2; break; case 3: W = w3; break;
            case 4: W = w4; break; case 5: W = w5; break;
            case 6: W = w6; break; default: W = w7; break;
        }
        const float4* s = reinterpret_cast<const float4*>(W + off);
        float4 a = s[0], b = s[1];
        union { s16x8 v; unsigned short u[8]; } p;
        p.u[0] = f2bf(a.x); p.u[1] = f2bf(a.y); p.u[2] = f2bf(a.z); p.u[3] = f2bf(a.w);
        p.u[4] = f2bf(b.x); p.u[5] = f2bf(b.y); p.u[6] = f2bf(b.z); p.u[7] = f2bf(b.w);
        *reinterpret_cast<s16x8*>(wb + gi) = p.v;
    }
}

// ---------------- mean aggregation: quarter-wave (16 lanes/node, 16B loads) ----------------
__global__ void __launch_bounds__(256) agg_kernel(const unsigned short* __restrict__ x,
                                                  const int* __restrict__ row,
                                                  const int* __restrict__ cnt,
                                                  const int* __restrict__ es,
                                                  unsigned short* __restrict__ mean) {
    int wave = (blockIdx.x * 256 + threadIdx.x) >> 6;
    int lane = threadIdx.x & 63;
    int ql = lane & 15;
    int n = wave * 4 + (lane >> 4);          // node in [0, 2*N_NODES)
    if (n >= 2 * N_NODES) return;
    const unsigned short* xs = x + (n >= N_NODES ? NF : 0);
    int start = row[n];
    int deg = cnt[n];
    float a0 = 0.f, a1 = 0.f, a2 = 0.f, a3 = 0.f, a4 = 0.f, a5 = 0.f, a6 = 0.f, a7 = 0.f;
    int qbase = lane & 48;
    for (int c = 0; c < deg; c += 16) {
        int m = min(16, deg - c);
        int eid = (ql < m) ? es[start + c + ql] : 0;
        int j = 0;
        for (; j + 4 <= m; j += 4) {
            int s0 = __shfl(eid, qbase + j,     64);
            int s1 = __shfl(eid, qbase + j + 1, 64);
            int s2 = __shfl(eid, qbase + j + 2, 64);
            int s3 = __shfl(eid, qbase + j + 3, 64);
            uint4 v0 = *reinterpret_cast<const uint4*>(xs + (size_t)s0 * 128 + ql * 8);
            uint4 v1 = *reinterpret_cast<const uint4*>(xs + (size_t)s1 * 128 + ql * 8);
            uint4 v2 = *reinterpret_cast<const uint4*>(xs + (size_t)s2 * 128 + ql * 8);
            uint4 v3 = *reinterpret_cast<const uint4*>(xs + (size_t)s3 * 128 + ql * 8);
            a0 += bflo(v0.x) + bflo(v1.x) + bflo(v2.x) + bflo(v3.x);
            a1 += bfhi(v0.x) + bfhi(v1.x) + bfhi(v2.x) + bfhi(v3.x);
            a2 += bflo(v0.y) + bflo(v1.y) + bflo(v2.y) + bflo(v3.y);
            a3 += bfhi(v0.y) + bfhi(v1.y) + bfhi(v2.y) + bfhi(v3.y);
            a4 += bflo(v0.z) + bflo(v1.z) + bflo(v2.z) + bflo(v3.z);
            a5 += bfhi(v0.z) + bfhi(v1.z) + bfhi(v2.z) + bfhi(v3.z);
            a6 += bflo(v0.w) + bflo(v1.w) + bflo(v2.w) + bflo(v3.w);
            a7 += bfhi(v0.w) + bfhi(v1.w) + bfhi(v2.w) + bfhi(v3.w);
        }
        for (; j < m; ++j) {
            int s = __shfl(eid, qbase + j, 64);
            uint4 v = *reinterpret_cast<const uint4*>(xs + (size_t)s * 128 + ql * 8);
            a0 += bflo(v.x); a1 += bfhi(v.x);
            a2 += bflo(v.y); a3 += bfhi(v.y);
            a4 += bflo(v.z); a5 += bfhi(v.z);
            a6 += bflo(v.w); a7 += bfhi(v.w);
        }
    }
    float inv = 1.0f / fmaxf((float)deg, 1.0f);
    uint4 o;
    o.x = (unsigned int)f2bf(a0 * inv) | ((unsigned int)f2bf(a1 * inv) << 16);
    o.y = (unsigned int)f2bf(a2 * inv) | ((unsigned int)f2bf(a3 * inv) << 16);
    o.z = (unsigned int)f2bf(a4 * inv) | ((unsigned int)f2bf(a5 * inv) << 16);
    o.w = (unsigned int)f2bf(a6 * inv) | ((unsigned int)f2bf(a7 * inv) << 16);
    *reinterpret_cast<uint4*>(mean + (size_t)n * 128 + ql * 8) = o;
}

// ---------------- MFMA GEMM: 128 nodes x 128 cols, 8 waves; blockIdx.y = set ----------------
__global__ void __launch_bounds__(512) gemm_mfma(const unsigned short* __restrict__ AmB,
                                                 const unsigned short* __restrict__ AxB,
                                                 const unsigned short* __restrict__ WBall,
                                                 const float* __restrict__ bias0,
                                                 const float* __restrict__ bias1,
                                                 unsigned short* __restrict__ outHB,
                                                 float* __restrict__ pool,
                                                 const int* __restrict__ batch,
                                                 int layer) {
    __shared__ s16x8 lds_a[2][512];   // [128 rows][4 slots of 8 bf16]
    __shared__ s16x8 lds_b[2][512];   // [128 rows][4 slots]

    const int tid = threadIdx.x;
    const int lane = tid & 63;
    const int w = tid >> 6;           // 0..7
    const int set = blockIdx.y;
    const int node0 = blockIdx.x * 128;

    const unsigned short* Am = AmB + (size_t)set * NF;
    const unsigned short* Ax = AxB + (size_t)set * NF;
    const unsigned short* Bl = WBall + (size_t)(set * 4 + layer * 2) * 16384;
    const unsigned short* Br = Bl + 16384;
    const float* bias = set ? bias1 : bias0;
    unsigned short* outH = outHB ? outHB + (size_t)set * NF : nullptr;
    const int poolBase = set * 128;

    const int wr = w >> 1;            // 0..3 : 32-row band
    const int wc = w & 1;             // 0..1 : 64-col half
    const int fr = lane & 15;
    const int fg = lane >> 4;

    f32x4 acc[2][4];
    #pragma unroll
    for (int mf = 0; mf < 2; ++mf)
        #pragma unroll
        for (int nf = 0; nf < 4; ++nf) acc[mf][nf] = (f32x4){0.f, 0.f, 0.f, 0.f};

    const int s_row = tid >> 2, s_slot = tid & 3;
    const int s_g = s_slot ^ ((s_row >> 1) & 3);
    const size_t a_off = (size_t)min(node0 + s_row, N_NODES - 1) * 128 + s_g * 8;
    const size_t b_off = (size_t)s_row * 128 + s_g * 8;

    const int arow0 = wr * 32 + fr;
    const int arow1 = arow0 + 16;
    const int aidx0 = arow0 * 4 + (fg ^ ((arow0 >> 1) & 3));
    const int aidx1 = arow1 * 4 + (fg ^ ((arow1 >> 1) & 3));
    int bidx[4];
    #pragma unroll
    for (int nf = 0; nf < 4; ++nf) {
        int br = wc * 64 + nf * 16 + fr;
        bidx[nf] = br * 4 + (fg ^ ((br >> 1) & 3));
    }

    #define LOAD_A(kc) (*reinterpret_cast<const s16x8*>(((kc) < 4 ? Am : Ax) + (((kc) & 3) * 32) + a_off))
    #define LOAD_B(kc) (*reinterpret_cast<const s16x8*>(((kc) < 4 ? Bl : Br) + (((kc) & 3) * 32) + b_off))

    {
        s16x8 ra = LOAD_A(0), rb = LOAD_B(0);
        lds_a[0][tid] = ra; lds_b[0][tid] = rb;
    }
    __syncthreads();

    #pragma unroll
    for (int kc = 0; kc < 8; ++kc) {
        const int cur = kc & 1;
        s16x8 ra, rb;
        if (kc < 7) { ra = LOAD_A(kc + 1); rb = LOAD_B(kc + 1); }
        s16x8 a0 = lds_a[cur][aidx0];
        s16x8 a1 = lds_a[cur][aidx1];
        #pragma unroll
        for (int nf = 0; nf < 4; ++nf) {
            s16x8 bv = lds_b[cur][bidx[nf]];
            acc[0][nf] = __builtin_amdgcn_mfma_f32_16x16x32_bf16(a0, bv, acc[0][nf], 0, 0, 0);
            acc[1][nf] = __builtin_amdgcn_mfma_f32_16x16x32_bf16(a1, bv, acc[1][nf], 0, 0, 0);
        }
        if (kc < 7) { lds_a[cur ^ 1][tid] = ra; lds_b[cur ^ 1][tid] = rb; }
        __syncthreads();
    }
    #undef LOAD_A
    #undef LOAD_B

    if (outH) {
        #pragma unroll
        for (int mf = 0; mf < 2; ++mf)
            #pragma unroll
            for (int nf = 0; nf < 4; ++nf) {
                int col = wc * 64 + nf * 16 + fr;
                float bv = bias[col];
                #pragma unroll
                for (int r = 0; r < 4; ++r) {
                    int node = node0 + wr * 32 + mf * 16 + fg * 4 + r;
                    if (node < N_NODES)
                        outH[(size_t)node * 128 + col] = f2bf(fmaxf(acc[mf][nf][r] + bv, 0.f));
                }
            }
    } else {
        int gids[2][4];
        #pragma unroll
        for (int mf = 0; mf < 2; ++mf)
            #pragma unroll
            for (int r = 0; r < 4; ++r) {
                int node = node0 + wr * 32 + mf * 16 + fg * 4 + r;
                gids[mf][r] = (node < N_NODES) ? batch[node] : -1;
            }
        #pragma unroll
        for (int nf = 0; nf < 4; ++nf) {
            int col = wc * 64 + nf * 16 + fr;
            float bv = bias[col];
            float* pbase = &pool[poolBase + col];
            int curg = -1; float s = 0.f;
            #pragma unroll
            for (int mf = 0; mf < 2; ++mf)
                #pragma unroll
                for (int r = 0; r < 4; ++r) {
                    int g = gids[mf][r];
                    if (g < 0) continue;
                    float v = fmaxf(acc[mf][nf][r] + bv, 0.f);
                    if (g != curg) {
                        if (curg >= 0) atomicAdd(pbase + (size_t)curg * 256, s);
                        curg = g; s = v;
                    } else s += v;
                }
            if (curg >= 0) atomicAdd(pbase + (size_t)curg * 256, s);
        }
    }
}

// ---------------- MLP head + log_softmax, one block per graph ----------------
__global__ void __launch_bounds__(128) head_kernel(const float* __restrict__ pool,
                                                   const float* __restrict__ W1, const float* __restrict__ bh1,
                                                   const float* __restrict__ W2, const float* __restrict__ bh2,
                                                   const float* __restrict__ W3, const float* __restrict__ bh3,
                                                   float* __restrict__ out) {
    __shared__ float xg[256];
    __shared__ float h1[128];
    __shared__ float h2[64];
    __shared__ float lg[2];
    int g = blockIdx.x, t = threadIdx.x;
    xg[t] = pool[(size_t)g * 256 + t];
    xg[t + 128] = pool[(size_t)g * 256 + 128 + t];
    __syncthreads();
    float s = bh1[t];
    for (int k = 0; k < 256; ++k) s += W1[t * 256 + k] * xg[k];
    h1[t] = fmaxf(s, 0.f);
    __syncthreads();
    if (t < 64) {
        float s2 = bh2[t];
        for (int k = 0; k < 128; ++k) s2 += W2[t * 128 + k] * h1[k];
        h2[t] = fmaxf(s2, 0.f);
    }
    __syncthreads();
    if (t < 2) {
        float s3 = bh3[t];
        for (int k = 0; k < 64; ++k) s3 += W3[t * 64 + k] * h2[k];
        lg[t] = s3;
    }
    __syncthreads();
    if (t == 0) {
        float m = fmaxf(lg[0], lg[1]);
        float lse = m + logf(expf(lg[0] - m) + expf(lg[1] - m));
        out[g * 2 + 0] = lg[0] - lse;
        out[g * 2 + 1] = lg[1] - lse;
    }
}

extern "C" void kernel_launch(void* const* d_in, const int* in_sizes, int n_in,
                              void* d_out, int out_size, void* d_ws, size_t ws_size,
                              hipStream_t stream) {
    const float* sc_x = (const float*)d_in[0];
    const float* fc_x = (const float*)d_in[1];
    const int* sc_e   = (const int*)d_in[2];
    const int* fc_e   = (const int*)d_in[3];
    const int* batch  = (const int*)d_in[4];
    const float* sc_Wl1 = (const float*)d_in[5];
    const float* sc_Wr1 = (const float*)d_in[6];
    const float* sc_b1  = (const float*)d_in[7];
    const float* sc_Wl2 = (const float*)d_in[8];
    const float* sc_Wr2 = (const float*)d_in[9];
    const float* sc_b2  = (const float*)d_in[10];
    const float* fc_Wl1 = (const float*)d_in[11];
    const float* fc_Wr1 = (const float*)d_in[12];
    const float* fc_b1  = (const float*)d_in[13];
    const float* fc_Wl2 = (const float*)d_in[14];
    const float* fc_Wr2 = (const float*)d_in[15];
    const float* fc_b2  = (const float*)d_in[16];
    const float* W1  = (const float*)d_in[17];
    const float* bh1 = (const float*)d_in[18];
    const float* W2  = (const float*)d_in[19];
    const float* bh2 = (const float*)d_in[20];
    const float* W3  = (const float*)d_in[21];
    const float* bh3 = (const float*)d_in[22];

    int* iw = (int*)d_ws;
    float* fw = (float*)d_ws;
    float* pool = fw + O_POOL;
    int* gcur   = iw + O_GCUR;
    int* row    = iw + O_ROW;
    int* cnt    = iw + O_CNT;
    int* es     = iw + O_ES;
    unsigned short* WB    = (unsigned short*)(iw + O_WB);
    unsigned short* xb    = (unsigned short*)(iw + O_XB);
    unsigned short* meanb = (unsigned short*)(iw + O_MEAN);
    unsigned short* hb    = (unsigned short*)(iw + O_HB);
    unsigned int* buf = (unsigned int*)(iw + O_MEAN);   // aliased: build-time only

    hipMemsetAsync(d_ws, 0, ZERO_BYTES, stream);

    // CSR build via 2-pass binned counting sort (scan folded into pass 2)
    bin_pass1<<<(2 * E_EDGES + 4095) / 4096, 512, 0, stream>>>(sc_e, fc_e, gcur, buf);
    bin_pass2<<<NBUCK, 256, 0, stream>>>(buf, gcur, row, cnt, es);

    cvt_all<<<6250 + 64, 256, 0, stream>>>(sc_x, fc_x,
                                           sc_Wl1, sc_Wr1, sc_Wl2, sc_Wr2,
                                           fc_Wl1, fc_Wr1, fc_Wl2, fc_Wr2, xb, WB);

    const int AGB = (2 * N_NODES + 15) / 16;    // 6250 blocks, 16 nodes/block
    dim3 gg((N_NODES + 127) / 128, 2);          // (391, 2)

    // layer 1 (both branches)
    agg_kernel<<<AGB, 256, 0, stream>>>(xb, row, cnt, es, meanb);
    gemm_mfma<<<gg, 512, 0, stream>>>(meanb, xb, WB, sc_b1, fc_b1, hb, nullptr, nullptr, 0);
    // layer 2 (both branches) + fused pool
    agg_kernel<<<AGB, 256, 0, stream>>>(hb, row, cnt, es, meanb);
    gemm_mfma<<<gg, 512, 0, stream>>>(meanb, hb, WB, sc_b2, fc_b2, nullptr, pool, batch, 1);

    head_kernel<<<G_GRAPHS, 128, 0, stream>>>(pool, W1, bh1, W2, bh2, W3, bh3, (float*)d_out);
}